// Round 1
// baseline (1377.997 us; speedup 1.0000x reference)
//
#include <hip/hip_runtime.h>
#include <math.h>

#define HH 256
#define WW 256
#define NN (HH * WW)

// ---------------------------------------------------------------------------
// Direct 3x3 conv + ReLU. One thread per output pixel, all COUT channels in
// registers. Input tile (18x18xCIN) staged in LDS. gridDim.z indexes the two
// submodel streams (xa / xb) which share weights.
// ---------------------------------------------------------------------------
template <int CIN, int COUT>
__global__ __launch_bounds__(256) void conv3x3_relu_kernel(
    const float* __restrict__ in, const float* __restrict__ w,
    const float* __restrict__ bias, float* __restrict__ out) {
  extern __shared__ float tile[];  // CIN * 18 * 18
  const int tx = threadIdx.x, ty = threadIdx.y;
  const int bx = blockIdx.x * 16, by = blockIdx.y * 16;
  const float* inz = in + (size_t)blockIdx.z * CIN * NN;
  float* outz = out + (size_t)blockIdx.z * COUT * NN;
  const int tid = ty * 16 + tx;
  const int TT = 18 * 18;

  for (int idx = tid; idx < CIN * TT; idx += 256) {
    int ci = idx / TT;
    int rem = idx - ci * TT;
    int yy = rem / 18, xx = rem - yy * 18;
    int gy = by + yy - 1, gx = bx + xx - 1;
    float v = 0.f;
    if (gy >= 0 && gy < HH && gx >= 0 && gx < WW)
      v = inz[ci * NN + gy * WW + gx];
    tile[idx] = v;
  }
  __syncthreads();

  float acc[COUT];
#pragma unroll
  for (int co = 0; co < COUT; ++co) acc[co] = bias[co];

  constexpr int CH = (CIN % 8 == 0) ? 8 : CIN;  // 48 -> 8, 3 -> 3
  for (int ci0 = 0; ci0 < CIN; ci0 += CH) {
    float v[CH * 9];
#pragma unroll
    for (int c = 0; c < CH; ++c) {
#pragma unroll
      for (int t = 0; t < 9; ++t)
        v[c * 9 + t] =
            tile[(ci0 + c) * TT + (ty + t / 3) * 18 + (tx + t % 3)];
    }
#pragma unroll
    for (int co = 0; co < COUT; ++co) {
      float s = acc[co];
      const float* __restrict__ wp = w + (co * CIN + ci0) * 9;
#pragma unroll
      for (int k = 0; k < CH * 9; ++k) s = fmaf(v[k], wp[k], s);
      acc[co] = s;
    }
  }

  const int p = (by + ty) * WW + (bx + tx);
#pragma unroll
  for (int co = 0; co < COUT; ++co)
    outz[co * NN + p] = fmaxf(acc[co], 0.f);
}

// ---------------------------------------------------------------------------
// a/b = relu4_out + 1x1 skip conv of the 3-channel input. blockIdx.y = stream.
// ---------------------------------------------------------------------------
__global__ __launch_bounds__(256) void skip_add_kernel(
    const float* __restrict__ t, const float* __restrict__ x,
    const float* __restrict__ sw, const float* __restrict__ sb,
    float* __restrict__ out) {
  const int z = blockIdx.y;
  const int p = blockIdx.x * 256 + threadIdx.x;
  const float* tz = t + (size_t)z * 24 * NN;
  const float* xz = x + (size_t)z * 3 * NN;
  float* oz = out + (size_t)z * 24 * NN;
  const float x0 = xz[p], x1 = xz[NN + p], x2 = xz[2 * NN + p];
#pragma unroll
  for (int co = 0; co < 24; ++co) {
    float s = sb[co];
    s = fmaf(x0, sw[co * 3 + 0], s);
    s = fmaf(x1, sw[co * 3 + 1], s);
    s = fmaf(x2, sw[co * 3 + 2], s);
    oz[co * NN + p] = tz[co * NN + p] + s;
  }
}

// ---------------------------------------------------------------------------
// Q = 1x1(b), Kmap = 1x1(a), Vmap = 1x1(a). One thread per pixel.
// ---------------------------------------------------------------------------
__global__ __launch_bounds__(256) void qkv_kernel(
    const float* __restrict__ a, const float* __restrict__ b,
    const float* __restrict__ qw, const float* __restrict__ qb,
    const float* __restrict__ kw, const float* __restrict__ kb,
    const float* __restrict__ vw, const float* __restrict__ vb,
    float* __restrict__ Q, float* __restrict__ K, float* __restrict__ V) {
  const int p = blockIdx.x * 256 + threadIdx.x;
  float av[24], bv[24];
#pragma unroll
  for (int c = 0; c < 24; ++c) {
    av[c] = a[c * NN + p];
    bv[c] = b[c * NN + p];
  }
#pragma unroll
  for (int co = 0; co < 24; ++co) {
    float sq = qb[co], sk = kb[co], sv = vb[co];
#pragma unroll
    for (int ci = 0; ci < 24; ++ci) {
      sq = fmaf(bv[ci], qw[co * 24 + ci], sq);
      sk = fmaf(av[ci], kw[co * 24 + ci], sk);
      sv = fmaf(av[ci], vw[co * 24 + ci], sv);
    }
    Q[co * NN + p] = sq;
    K[co * NN + p] = sk;
    V[co * NN + p] = sv;
  }
}

// ---------------------------------------------------------------------------
// 7x7 local attention. 16x16 pixel tile/block; K then V staged (zero-padded)
// into one 22x22x24 LDS buffer laid out [y][x][float4-channel] for b128 reads.
// Zero-padded K gives score 0 at borders (matches reference unfold+softmax).
// ---------------------------------------------------------------------------
__global__ __launch_bounds__(256) void attn_kernel(
    const float* __restrict__ Qm, const float* __restrict__ Km,
    const float* __restrict__ Vm, const float* __restrict__ ab,
    float* __restrict__ out) {
  extern __shared__ float4 sm4[];  // 22*22*6 float4 = 46464 B
  const int tx = threadIdx.x, ty = threadIdx.y;
  const int bx = blockIdx.x * 16, by = blockIdx.y * 16;
  const int tid = ty * 16 + tx;
  const int TOT = 22 * 22 * 6;

  // ---- stage K tile
  for (int idx = tid; idx < TOT; idx += 256) {
    int j = idx % 6;
    int pix = idx / 6;
    int xx = pix % 22, yy = pix / 22;
    int gy = by + yy - 3, gx = bx + xx - 3;
    float4 kk = make_float4(0.f, 0.f, 0.f, 0.f);
    if (gy >= 0 && gy < HH && gx >= 0 && gx < WW) {
      int base = gy * WW + gx;
      kk.x = Km[(4 * j + 0) * NN + base];
      kk.y = Km[(4 * j + 1) * NN + base];
      kk.z = Km[(4 * j + 2) * NN + base];
      kk.w = Km[(4 * j + 3) * NN + base];
    }
    sm4[idx] = kk;
  }
  __syncthreads();

  const int p = (by + ty) * WW + (bx + tx);
  float4 q4[6];
#pragma unroll
  for (int j = 0; j < 6; ++j) {
    q4[j].x = Qm[(4 * j + 0) * NN + p];
    q4[j].y = Qm[(4 * j + 1) * NN + p];
    q4[j].z = Qm[(4 * j + 2) * NN + p];
    q4[j].w = Qm[(4 * j + 3) * NN + p];
  }

  float s[49];
#pragma unroll
  for (int pp = 0; pp < 49; ++pp) {
    int dy = pp / 7, dx = pp % 7;
    int base = ((ty + dy) * 22 + (tx + dx)) * 6;
    float d = 0.f;
#pragma unroll
    for (int j = 0; j < 6; ++j) {
      float4 kk = sm4[base + j];
      d = fmaf(q4[j].x, kk.x, d);
      d = fmaf(q4[j].y, kk.y, d);
      d = fmaf(q4[j].z, kk.z, d);
      d = fmaf(q4[j].w, kk.w, d);
    }
    s[pp] = d * 0.20412414523193154f;  // 1/sqrt(24)
  }
  __syncthreads();  // everyone done reading K

  // ---- stage V tile (reuse LDS)
  for (int idx = tid; idx < TOT; idx += 256) {
    int j = idx % 6;
    int pix = idx / 6;
    int xx = pix % 22, yy = pix / 22;
    int gy = by + yy - 3, gx = bx + xx - 3;
    float4 vv = make_float4(0.f, 0.f, 0.f, 0.f);
    if (gy >= 0 && gy < HH && gx >= 0 && gx < WW) {
      int base = gy * WW + gx;
      vv.x = Vm[(4 * j + 0) * NN + base];
      vv.y = Vm[(4 * j + 1) * NN + base];
      vv.z = Vm[(4 * j + 2) * NN + base];
      vv.w = Vm[(4 * j + 3) * NN + base];
    }
    sm4[idx] = vv;
  }
  __syncthreads();

  // ---- softmax over 49 positions
  float m = s[0];
#pragma unroll
  for (int pp = 1; pp < 49; ++pp) m = fmaxf(m, s[pp]);
  float den = 0.f;
#pragma unroll
  for (int pp = 0; pp < 49; ++pp) {
    float e = __expf(s[pp] - m);
    s[pp] = e;
    den += e;
  }
  const float inv = 1.f / den;

  float4 y4[6];
#pragma unroll
  for (int j = 0; j < 6; ++j) y4[j] = make_float4(0.f, 0.f, 0.f, 0.f);
#pragma unroll
  for (int pp = 0; pp < 49; ++pp) {
    int dy = pp / 7, dx = pp % 7;
    int base = ((ty + dy) * 22 + (tx + dx)) * 6;
    float wgt = s[pp] * inv;
#pragma unroll
    for (int j = 0; j < 6; ++j) {
      float4 vv = sm4[base + j];
      y4[j].x = fmaf(wgt, vv.x, y4[j].x);
      y4[j].y = fmaf(wgt, vv.y, y4[j].y);
      y4[j].z = fmaf(wgt, vv.z, y4[j].z);
      y4[j].w = fmaf(wgt, vv.w, y4[j].w);
    }
  }

  const float* a = ab;
  const float* b = ab + 24 * NN;
#pragma unroll
  for (int j = 0; j < 6; ++j) {
    out[(4 * j + 0) * NN + p] = y4[j].x + a[(4 * j + 0) * NN + p];
    out[(4 * j + 1) * NN + p] = y4[j].y + a[(4 * j + 1) * NN + p];
    out[(4 * j + 2) * NN + p] = y4[j].z + a[(4 * j + 2) * NN + p];
    out[(4 * j + 3) * NN + p] = y4[j].w + a[(4 * j + 3) * NN + p];
  }
#pragma unroll
  for (int c = 0; c < 24; ++c)
    out[(24 + c) * NN + p] = b[c * NN + p];
}

// ---------------------------------------------------------------------------
extern "C" void kernel_launch(void* const* d_in, const int* in_sizes, int n_in,
                              void* d_out, int out_size, void* d_ws,
                              size_t ws_size, hipStream_t stream) {
  const float* x = (const float*)d_in[0];
  const float* w0 = (const float*)d_in[1];
  const float* b0 = (const float*)d_in[2];
  const float* w1 = (const float*)d_in[3];
  const float* b1 = (const float*)d_in[4];
  const float* w2 = (const float*)d_in[5];
  const float* b2 = (const float*)d_in[6];
  const float* w3 = (const float*)d_in[7];
  const float* b3 = (const float*)d_in[8];
  const float* sw = (const float*)d_in[9];
  const float* sb = (const float*)d_in[10];
  const float* qw = (const float*)d_in[11];
  const float* qb = (const float*)d_in[12];
  const float* kw = (const float*)d_in[13];
  const float* kb = (const float*)d_in[14];
  const float* vw = (const float*)d_in[15];
  const float* vb = (const float*)d_in[16];
  float* out = (float*)d_out;
  float* ws = (float*)d_ws;

  // workspace layout (floats):
  float* t0 = ws;                    // 2*48*NN
  float* t1 = ws + 2 * 48 * NN;      // 2*48*NN
  float* AB = ws + 4 * 48 * NN;      // 2*24*NN  (a then b)
  // after the conv chain t0 is dead -> reuse for Q/K/V maps (24*NN each)
  float* Qb = t0;
  float* Kb = t0 + 24 * NN;
  float* Vb = t0 + 48 * NN;

  dim3 cblk(16, 16, 1);
  dim3 cgrd(16, 16, 2);  // z = {xa, xb} streams, shared weights

  conv3x3_relu_kernel<3, 48><<<cgrd, cblk, 3 * 324 * 4, stream>>>(x, w0, b0, t0);
  conv3x3_relu_kernel<48, 48><<<cgrd, cblk, 48 * 324 * 4, stream>>>(t0, w1, b1, t1);
  conv3x3_relu_kernel<48, 48><<<cgrd, cblk, 48 * 324 * 4, stream>>>(t1, w2, b2, t0);
  conv3x3_relu_kernel<48, 24><<<cgrd, cblk, 48 * 324 * 4, stream>>>(t0, w3, b3, t1);

  skip_add_kernel<<<dim3(256, 2), dim3(256), 0, stream>>>(t1, x, sw, sb, AB);

  qkv_kernel<<<dim3(256), dim3(256), 0, stream>>>(AB, AB + 24 * NN, qw, qb, kw,
                                                  kb, vw, vb, Qb, Kb, Vb);

  attn_kernel<<<dim3(16, 16), cblk, 22 * 22 * 6 * 16, stream>>>(Qb, Kb, Vb, AB,
                                                                out);
}

// Round 2
// 1272.772 us; speedup vs baseline: 1.0827x; 1.0827x over previous
//
#include <hip/hip_runtime.h>
#include <math.h>

#define HH 256
#define WW 256
#define NN (HH * WW)

// ---------------------------------------------------------------------------
// Direct 3x3 conv + ReLU. One thread per output pixel, all COUT channels in
// registers. Input tile staged in LDS in halves of <=24 channels (31 KB) so
// LDS doesn't cap occupancy at 2 blocks/CU. ci-chunk of 4 keeps the live set
// to acc[COUT] + v[36] (~100 VGPR) so the patch survives the full co-loop
// (R1 failure mode: CH=8 + full-CIN tile forced LDS re-reads inside co-loop).
// gridDim.z indexes the two submodel streams (xa / xb), shared weights.
// ---------------------------------------------------------------------------
template <int CIN, int COUT>
__global__ __launch_bounds__(256, 4) void conv3x3_relu_kernel(
    const float* __restrict__ in, const float* __restrict__ w,
    const float* __restrict__ bias, float* __restrict__ out) {
  constexpr int HALF = (CIN >= 24) ? 24 : CIN;  // channels per LDS stage
  constexpr int NH = CIN / HALF;                // 2 for CIN=48, 1 for CIN=3
  constexpr int TT = 18 * 18;
  extern __shared__ float tile[];  // HALF * 324 floats

  const int tx = threadIdx.x, ty = threadIdx.y;
  const int bx = blockIdx.x * 16, by = blockIdx.y * 16;
  const float* inz = in + (size_t)blockIdx.z * CIN * NN;
  float* outz = out + (size_t)blockIdx.z * COUT * NN;
  const int tid = ty * 16 + tx;

  float acc[COUT];
#pragma unroll
  for (int co = 0; co < COUT; ++co) acc[co] = bias[co];

  for (int h = 0; h < NH; ++h) {
    // ---- stage channels [h*HALF, h*HALF+HALF) into LDS
    for (int idx = tid; idx < HALF * TT; idx += 256) {
      int cl = idx / TT;
      int rem = idx - cl * TT;
      int yy = rem / 18, xx = rem - yy * 18;
      int gy = by + yy - 1, gx = bx + xx - 1;
      float v = 0.f;
      if (gy >= 0 && gy < HH && gx >= 0 && gx < WW)
        v = inz[(h * HALF + cl) * NN + gy * WW + gx];
      tile[idx] = v;
    }
    __syncthreads();

    constexpr int CH = (HALF % 4 == 0) ? 4 : HALF;  // 4 for 24, 3 for 3
#pragma unroll 1
    for (int c0 = 0; c0 < HALF; c0 += CH) {
      float v[CH * 9];
#pragma unroll
      for (int c = 0; c < CH; ++c) {
#pragma unroll
        for (int t = 0; t < 9; ++t)
          v[c * 9 + t] =
              tile[(c0 + c) * TT + (ty + t / 3) * 18 + (tx + t % 3)];
      }
#pragma unroll
      for (int co = 0; co < COUT; ++co) {
        float s = acc[co];
        const float* __restrict__ wp = w + (co * CIN + h * HALF + c0) * 9;
#pragma unroll
        for (int k = 0; k < CH * 9; ++k) s = fmaf(v[k], wp[k], s);
        acc[co] = s;
      }
    }
    __syncthreads();  // all reads done before next half overwrites LDS
  }

  const int p = (by + ty) * WW + (bx + tx);
#pragma unroll
  for (int co = 0; co < COUT; ++co)
    outz[co * NN + p] = fmaxf(acc[co], 0.f);
}

// ---------------------------------------------------------------------------
// a/b = relu4_out + 1x1 skip conv of the 3-channel input. blockIdx.y = stream.
// ---------------------------------------------------------------------------
__global__ __launch_bounds__(256) void skip_add_kernel(
    const float* __restrict__ t, const float* __restrict__ x,
    const float* __restrict__ sw, const float* __restrict__ sb,
    float* __restrict__ out) {
  const int z = blockIdx.y;
  const int p = blockIdx.x * 256 + threadIdx.x;
  const float* tz = t + (size_t)z * 24 * NN;
  const float* xz = x + (size_t)z * 3 * NN;
  float* oz = out + (size_t)z * 24 * NN;
  const float x0 = xz[p], x1 = xz[NN + p], x2 = xz[2 * NN + p];
#pragma unroll
  for (int co = 0; co < 24; ++co) {
    float s = sb[co];
    s = fmaf(x0, sw[co * 3 + 0], s);
    s = fmaf(x1, sw[co * 3 + 1], s);
    s = fmaf(x2, sw[co * 3 + 2], s);
    oz[co * NN + p] = tz[co * NN + p] + s;
  }
}

// ---------------------------------------------------------------------------
// Q = 1x1(b), Kmap = 1x1(a), Vmap = 1x1(a). One thread per pixel.
// ---------------------------------------------------------------------------
__global__ __launch_bounds__(256) void qkv_kernel(
    const float* __restrict__ a, const float* __restrict__ b,
    const float* __restrict__ qw, const float* __restrict__ qb,
    const float* __restrict__ kw, const float* __restrict__ kb,
    const float* __restrict__ vw, const float* __restrict__ vb,
    float* __restrict__ Q, float* __restrict__ K, float* __restrict__ V) {
  const int p = blockIdx.x * 256 + threadIdx.x;
  float av[24], bv[24];
#pragma unroll
  for (int c = 0; c < 24; ++c) {
    av[c] = a[c * NN + p];
    bv[c] = b[c * NN + p];
  }
#pragma unroll
  for (int co = 0; co < 24; ++co) {
    float sq = qb[co], sk = kb[co], sv = vb[co];
#pragma unroll
    for (int ci = 0; ci < 24; ++ci) {
      sq = fmaf(bv[ci], qw[co * 24 + ci], sq);
      sk = fmaf(av[ci], kw[co * 24 + ci], sk);
      sv = fmaf(av[ci], vw[co * 24 + ci], sv);
    }
    Q[co * NN + p] = sq;
    K[co * NN + p] = sk;
    V[co * NN + p] = sv;
  }
}

// ---------------------------------------------------------------------------
// 7x7 local attention. 16x16 pixel tile/block; K then V staged (zero-padded)
// into one 22x22x24 LDS buffer laid out [y][x][float4-channel] for b128 reads.
// Zero-padded K gives score 0 at borders (matches reference unfold+softmax).
// ---------------------------------------------------------------------------
__global__ __launch_bounds__(256) void attn_kernel(
    const float* __restrict__ Qm, const float* __restrict__ Km,
    const float* __restrict__ Vm, const float* __restrict__ ab,
    float* __restrict__ out) {
  extern __shared__ float4 sm4[];  // 22*22*6 float4 = 46464 B
  const int tx = threadIdx.x, ty = threadIdx.y;
  const int bx = blockIdx.x * 16, by = blockIdx.y * 16;
  const int tid = ty * 16 + tx;
  const int TOT = 22 * 22 * 6;

  // ---- stage K tile
  for (int idx = tid; idx < TOT; idx += 256) {
    int j = idx % 6;
    int pix = idx / 6;
    int xx = pix % 22, yy = pix / 22;
    int gy = by + yy - 3, gx = bx + xx - 3;
    float4 kk = make_float4(0.f, 0.f, 0.f, 0.f);
    if (gy >= 0 && gy < HH && gx >= 0 && gx < WW) {
      int base = gy * WW + gx;
      kk.x = Km[(4 * j + 0) * NN + base];
      kk.y = Km[(4 * j + 1) * NN + base];
      kk.z = Km[(4 * j + 2) * NN + base];
      kk.w = Km[(4 * j + 3) * NN + base];
    }
    sm4[idx] = kk;
  }
  __syncthreads();

  const int p = (by + ty) * WW + (bx + tx);
  float4 q4[6];
#pragma unroll
  for (int j = 0; j < 6; ++j) {
    q4[j].x = Qm[(4 * j + 0) * NN + p];
    q4[j].y = Qm[(4 * j + 1) * NN + p];
    q4[j].z = Qm[(4 * j + 2) * NN + p];
    q4[j].w = Qm[(4 * j + 3) * NN + p];
  }

  float s[49];
#pragma unroll
  for (int pp = 0; pp < 49; ++pp) {
    int dy = pp / 7, dx = pp % 7;
    int base = ((ty + dy) * 22 + (tx + dx)) * 6;
    float d = 0.f;
#pragma unroll
    for (int j = 0; j < 6; ++j) {
      float4 kk = sm4[base + j];
      d = fmaf(q4[j].x, kk.x, d);
      d = fmaf(q4[j].y, kk.y, d);
      d = fmaf(q4[j].z, kk.z, d);
      d = fmaf(q4[j].w, kk.w, d);
    }
    s[pp] = d * 0.20412414523193154f;  // 1/sqrt(24)
  }
  __syncthreads();  // everyone done reading K

  // ---- stage V tile (reuse LDS)
  for (int idx = tid; idx < TOT; idx += 256) {
    int j = idx % 6;
    int pix = idx / 6;
    int xx = pix % 22, yy = pix / 22;
    int gy = by + yy - 3, gx = bx + xx - 3;
    float4 vv = make_float4(0.f, 0.f, 0.f, 0.f);
    if (gy >= 0 && gy < HH && gx >= 0 && gx < WW) {
      int base = gy * WW + gx;
      vv.x = Vm[(4 * j + 0) * NN + base];
      vv.y = Vm[(4 * j + 1) * NN + base];
      vv.z = Vm[(4 * j + 2) * NN + base];
      vv.w = Vm[(4 * j + 3) * NN + base];
    }
    sm4[idx] = vv;
  }
  __syncthreads();

  // ---- softmax over 49 positions
  float m = s[0];
#pragma unroll
  for (int pp = 1; pp < 49; ++pp) m = fmaxf(m, s[pp]);
  float den = 0.f;
#pragma unroll
  for (int pp = 0; pp < 49; ++pp) {
    float e = __expf(s[pp] - m);
    s[pp] = e;
    den += e;
  }
  const float inv = 1.f / den;

  float4 y4[6];
#pragma unroll
  for (int j = 0; j < 6; ++j) y4[j] = make_float4(0.f, 0.f, 0.f, 0.f);
#pragma unroll
  for (int pp = 0; pp < 49; ++pp) {
    int dy = pp / 7, dx = pp % 7;
    int base = ((ty + dy) * 22 + (tx + dx)) * 6;
    float wgt = s[pp] * inv;
#pragma unroll
    for (int j = 0; j < 6; ++j) {
      float4 vv = sm4[base + j];
      y4[j].x = fmaf(wgt, vv.x, y4[j].x);
      y4[j].y = fmaf(wgt, vv.y, y4[j].y);
      y4[j].z = fmaf(wgt, vv.z, y4[j].z);
      y4[j].w = fmaf(wgt, vv.w, y4[j].w);
    }
  }

  const float* a = ab;
  const float* b = ab + 24 * NN;
#pragma unroll
  for (int j = 0; j < 6; ++j) {
    out[(4 * j + 0) * NN + p] = y4[j].x + a[(4 * j + 0) * NN + p];
    out[(4 * j + 1) * NN + p] = y4[j].y + a[(4 * j + 1) * NN + p];
    out[(4 * j + 2) * NN + p] = y4[j].z + a[(4 * j + 2) * NN + p];
    out[(4 * j + 3) * NN + p] = y4[j].w + a[(4 * j + 3) * NN + p];
  }
#pragma unroll
  for (int c = 0; c < 24; ++c)
    out[(24 + c) * NN + p] = b[c * NN + p];
}

// ---------------------------------------------------------------------------
extern "C" void kernel_launch(void* const* d_in, const int* in_sizes, int n_in,
                              void* d_out, int out_size, void* d_ws,
                              size_t ws_size, hipStream_t stream) {
  const float* x = (const float*)d_in[0];
  const float* w0 = (const float*)d_in[1];
  const float* b0 = (const float*)d_in[2];
  const float* w1 = (const float*)d_in[3];
  const float* b1 = (const float*)d_in[4];
  const float* w2 = (const float*)d_in[5];
  const float* b2 = (const float*)d_in[6];
  const float* w3 = (const float*)d_in[7];
  const float* b3 = (const float*)d_in[8];
  const float* sw = (const float*)d_in[9];
  const float* sb = (const float*)d_in[10];
  const float* qw = (const float*)d_in[11];
  const float* qb = (const float*)d_in[12];
  const float* kw = (const float*)d_in[13];
  const float* kb = (const float*)d_in[14];
  const float* vw = (const float*)d_in[15];
  const float* vb = (const float*)d_in[16];
  float* out = (float*)d_out;
  float* ws = (float*)d_ws;

  // workspace layout (floats):
  float* t0 = ws;                    // 2*48*NN
  float* t1 = ws + 2 * 48 * NN;      // 2*48*NN
  float* AB = ws + 4 * 48 * NN;      // 2*24*NN  (a then b)
  // after the conv chain t0 is dead -> reuse for Q/K/V maps (24*NN each)
  float* Qb = t0;
  float* Kb = t0 + 24 * NN;
  float* Vb = t0 + 48 * NN;

  dim3 cblk(16, 16, 1);
  dim3 cgrd(16, 16, 2);  // z = {xa, xb} streams, shared weights

  const int smem3 = 3 * 324 * 4;    // CIN=3 tile (single stage)
  const int smem48 = 24 * 324 * 4;  // CIN=48 staged in 24-ch halves

  conv3x3_relu_kernel<3, 48><<<cgrd, cblk, smem3, stream>>>(x, w0, b0, t0);
  conv3x3_relu_kernel<48, 48><<<cgrd, cblk, smem48, stream>>>(t0, w1, b1, t1);
  conv3x3_relu_kernel<48, 48><<<cgrd, cblk, smem48, stream>>>(t1, w2, b2, t0);
  conv3x3_relu_kernel<48, 24><<<cgrd, cblk, smem48, stream>>>(t0, w3, b3, t1);

  skip_add_kernel<<<dim3(256, 2), dim3(256), 0, stream>>>(t1, x, sw, sb, AB);

  qkv_kernel<<<dim3(256), dim3(256), 0, stream>>>(AB, AB + 24 * NN, qw, qb, kw,
                                                  kb, vw, vb, Qb, Kb, Vb);

  attn_kernel<<<dim3(16, 16), cblk, 22 * 22 * 6 * 16, stream>>>(Qb, Kb, Vb, AB,
                                                                out);
}

// Round 3
// 492.747 us; speedup vs baseline: 2.7966x; 2.5830x over previous
//
#include <hip/hip_runtime.h>
#include <math.h>

#define HH 256
#define WW 256
#define NN (HH * WW)

// ---------------------------------------------------------------------------
// Restructured direct 3x3 conv + ReLU.
// Block = 512 threads = 8 waves. Wave w owns co-group [w*CPW, (w+1)*CPW).
// Each thread computes 4 vertically adjacent pixels of a 16x16 tile, so a
// 6x3 patch (18 LDS reads) feeds CPW*9*4 FMAs per input channel, and each
// weight value (uniform per wave -> SGPR) feeds 4 FMAs.
// Input staged in LDS in <=24-channel halves (31 KB -> 2 blocks/CU, 16 waves).
// Weights come pre-repacked into 64-float aligned slices per (ci, wave) so
// the 54 (or 27) scalar loads batch into s_load_dwordx16 runs with ONE
// lgkmcnt drain per 432-cycle FMA block (R2 failure: drain every 72 cyc).
// ---------------------------------------------------------------------------
template <int CIN, int COUT>
__global__ __launch_bounds__(512, 4) void conv3x3_v2(
    const float* __restrict__ in, const float* __restrict__ wr,
    const float* __restrict__ bias, float* __restrict__ out) {
  constexpr int HALF = (CIN >= 24) ? 24 : CIN;  // channels per LDS stage
  constexpr int NH = CIN / HALF;
  constexpr int CPW = COUT / 8;  // co per wave: 6 (COUT=48) or 3 (COUT=24)
  constexpr int TT = 18 * 18;
  extern __shared__ float tile[];  // HALF * TT floats

  const int tid = threadIdx.x;
  const int wg = __builtin_amdgcn_readfirstlane(tid >> 6);  // wave-uniform
  const int s = tid & 63;
  const int x = s & 15;
  const int y0 = (s >> 4) * 4;  // 4 vertical pixels y0..y0+3
  const int bx = blockIdx.x * 16, by = blockIdx.y * 16;
  const float* inz = in + (size_t)blockIdx.z * CIN * NN;
  float* outz = out + (size_t)blockIdx.z * COUT * NN;

  float acc[CPW][4];
#pragma unroll
  for (int c = 0; c < CPW; ++c) {
    const float b = bias[wg * CPW + c];
#pragma unroll
    for (int i = 0; i < 4; ++i) acc[c][i] = b;
  }

  for (int h = 0; h < NH; ++h) {
    // ---- stage channels [h*HALF, h*HALF+HALF) into LDS
    for (int idx = tid; idx < HALF * TT; idx += 512) {
      int cl = idx / TT;
      int rem = idx - cl * TT;
      int yy = rem / 18, xx = rem - yy * 18;
      int gy = by + yy - 1, gx = bx + xx - 1;
      float v = 0.f;
      if (gy >= 0 && gy < HH && gx >= 0 && gx < WW)
        v = inz[(h * HALF + cl) * NN + gy * WW + gx];
      tile[idx] = v;
    }
    __syncthreads();

#pragma unroll 1  // keep weight SGPR footprint = one ci-step (54 floats)
    for (int ci = 0; ci < HALF; ++ci) {
      float pr[6][3];  // rows y0..y0+5, cols x..x+2 (banks: 2-way = free)
      const float* tp = tile + ci * TT + y0 * 18 + x;
#pragma unroll
      for (int r = 0; r < 6; ++r)
#pragma unroll
        for (int c = 0; c < 3; ++c) pr[r][c] = tp[r * 18 + c];

      const float* wp = wr + ((h * HALF + ci) * 8 + wg) * 64;  // 256B aligned
#pragma unroll
      for (int c = 0; c < CPW; ++c)
#pragma unroll
        for (int dy = 0; dy < 3; ++dy)
#pragma unroll
          for (int dx = 0; dx < 3; ++dx) {
            const float wv = wp[c * 9 + dy * 3 + dx];
#pragma unroll
            for (int i = 0; i < 4; ++i)
              acc[c][i] = fmaf(pr[dy + i][dx], wv, acc[c][i]);
          }
    }
    __syncthreads();
  }

  const int px = bx + x;
#pragma unroll
  for (int c = 0; c < CPW; ++c) {
    const int co = wg * CPW + c;
#pragma unroll
    for (int i = 0; i < 4; ++i)
      outz[co * NN + (by + y0 + i) * WW + px] = fmaxf(acc[c][i], 0.f);
  }
}

// ---------------------------------------------------------------------------
// Repack conv weights [COUT][CIN][3][3] -> per (ci-step, wave) slices of 64
// floats: wr[(step*8 + wg)*64 + cj*9 + k] = w[(wg*CPW+cj)][step][k].
// steps: layer0 3, layers1-3 48 each -> 147 slices * 512 floats.
// ---------------------------------------------------------------------------
__global__ __launch_bounds__(256) void repack_weights(
    const float* __restrict__ w0, const float* __restrict__ w1,
    const float* __restrict__ w2, const float* __restrict__ w3,
    float* __restrict__ wr) {
  const int b = blockIdx.x;  // 0..146 = one (layer, ci-step)
  const float* src;
  float* dst;
  int CINl, CPW, step;
  if (b < 3) {
    src = w0; dst = wr; CINl = 3; CPW = 6; step = b;
  } else if (b < 51) {
    src = w1; dst = wr + 3 * 512; CINl = 48; CPW = 6; step = b - 3;
  } else if (b < 99) {
    src = w2; dst = wr + 51 * 512; CINl = 48; CPW = 6; step = b - 51;
  } else {
    src = w3; dst = wr + 99 * 512; CINl = 48; CPW = 3; step = b - 99;
  }
  dst += step * 512;
  const int tot = 8 * CPW * 9;
  for (int e = threadIdx.x; e < tot; e += 256) {
    int wgrp = e / (CPW * 9);
    int r = e - wgrp * (CPW * 9);
    int cj = r / 9, kk = r - cj * 9;
    int co = wgrp * CPW + cj;
    dst[wgrp * 64 + cj * 9 + kk] = src[(co * CINl + step) * 9 + kk];
  }
}

// ---------------------------------------------------------------------------
// a/b = relu4_out + 1x1 skip conv of the 3-channel input. blockIdx.y = stream.
// ---------------------------------------------------------------------------
__global__ __launch_bounds__(256) void skip_add_kernel(
    const float* __restrict__ t, const float* __restrict__ x,
    const float* __restrict__ sw, const float* __restrict__ sb,
    float* __restrict__ out) {
  const int z = blockIdx.y;
  const int p = blockIdx.x * 256 + threadIdx.x;
  const float* tz = t + (size_t)z * 24 * NN;
  const float* xz = x + (size_t)z * 3 * NN;
  float* oz = out + (size_t)z * 24 * NN;
  const float x0 = xz[p], x1 = xz[NN + p], x2 = xz[2 * NN + p];
#pragma unroll
  for (int co = 0; co < 24; ++co) {
    float s = sb[co];
    s = fmaf(x0, sw[co * 3 + 0], s);
    s = fmaf(x1, sw[co * 3 + 1], s);
    s = fmaf(x2, sw[co * 3 + 2], s);
    oz[co * NN + p] = tz[co * NN + p] + s;
  }
}

// ---------------------------------------------------------------------------
// Q = 1x1(b), Kmap = 1x1(a), Vmap = 1x1(a). One thread per pixel.
// ---------------------------------------------------------------------------
__global__ __launch_bounds__(256) void qkv_kernel(
    const float* __restrict__ a, const float* __restrict__ b,
    const float* __restrict__ qw, const float* __restrict__ qb,
    const float* __restrict__ kw, const float* __restrict__ kb,
    const float* __restrict__ vw, const float* __restrict__ vb,
    float* __restrict__ Q, float* __restrict__ K, float* __restrict__ V) {
  const int p = blockIdx.x * 256 + threadIdx.x;
  float av[24], bv[24];
#pragma unroll
  for (int c = 0; c < 24; ++c) {
    av[c] = a[c * NN + p];
    bv[c] = b[c * NN + p];
  }
#pragma unroll
  for (int co = 0; co < 24; ++co) {
    float sq = qb[co], sk = kb[co], sv = vb[co];
#pragma unroll
    for (int ci = 0; ci < 24; ++ci) {
      sq = fmaf(bv[ci], qw[co * 24 + ci], sq);
      sk = fmaf(av[ci], kw[co * 24 + ci], sk);
      sv = fmaf(av[ci], vw[co * 24 + ci], sv);
    }
    Q[co * NN + p] = sq;
    K[co * NN + p] = sk;
    V[co * NN + p] = sv;
  }
}

// ---------------------------------------------------------------------------
// 7x7 local attention. 16x16 pixel tile/block; K then V staged (zero-padded)
// into one 22x22x24 LDS buffer laid out [y][x][float4-channel].
// Zero-padded K gives score 0 at borders (matches reference unfold+softmax).
// ---------------------------------------------------------------------------
__global__ __launch_bounds__(256) void attn_kernel(
    const float* __restrict__ Qm, const float* __restrict__ Km,
    const float* __restrict__ Vm, const float* __restrict__ ab,
    float* __restrict__ out) {
  extern __shared__ float4 sm4[];  // 22*22*6 float4 = 46464 B
  const int tx = threadIdx.x, ty = threadIdx.y;
  const int bx = blockIdx.x * 16, by = blockIdx.y * 16;
  const int tid = ty * 16 + tx;
  const int TOT = 22 * 22 * 6;

  for (int idx = tid; idx < TOT; idx += 256) {
    int j = idx % 6;
    int pix = idx / 6;
    int xx = pix % 22, yy = pix / 22;
    int gy = by + yy - 3, gx = bx + xx - 3;
    float4 kk = make_float4(0.f, 0.f, 0.f, 0.f);
    if (gy >= 0 && gy < HH && gx >= 0 && gx < WW) {
      int base = gy * WW + gx;
      kk.x = Km[(4 * j + 0) * NN + base];
      kk.y = Km[(4 * j + 1) * NN + base];
      kk.z = Km[(4 * j + 2) * NN + base];
      kk.w = Km[(4 * j + 3) * NN + base];
    }
    sm4[idx] = kk;
  }
  __syncthreads();

  const int p = (by + ty) * WW + (bx + tx);
  float4 q4[6];
#pragma unroll
  for (int j = 0; j < 6; ++j) {
    q4[j].x = Qm[(4 * j + 0) * NN + p];
    q4[j].y = Qm[(4 * j + 1) * NN + p];
    q4[j].z = Qm[(4 * j + 2) * NN + p];
    q4[j].w = Qm[(4 * j + 3) * NN + p];
  }

  float s[49];
#pragma unroll
  for (int pp = 0; pp < 49; ++pp) {
    int dy = pp / 7, dx = pp % 7;
    int base = ((ty + dy) * 22 + (tx + dx)) * 6;
    float d = 0.f;
#pragma unroll
    for (int j = 0; j < 6; ++j) {
      float4 kk = sm4[base + j];
      d = fmaf(q4[j].x, kk.x, d);
      d = fmaf(q4[j].y, kk.y, d);
      d = fmaf(q4[j].z, kk.z, d);
      d = fmaf(q4[j].w, kk.w, d);
    }
    s[pp] = d * 0.20412414523193154f;  // 1/sqrt(24)
  }
  __syncthreads();

  for (int idx = tid; idx < TOT; idx += 256) {
    int j = idx % 6;
    int pix = idx / 6;
    int xx = pix % 22, yy = pix / 22;
    int gy = by + yy - 3, gx = bx + xx - 3;
    float4 vv = make_float4(0.f, 0.f, 0.f, 0.f);
    if (gy >= 0 && gy < HH && gx >= 0 && gx < WW) {
      int base = gy * WW + gx;
      vv.x = Vm[(4 * j + 0) * NN + base];
      vv.y = Vm[(4 * j + 1) * NN + base];
      vv.z = Vm[(4 * j + 2) * NN + base];
      vv.w = Vm[(4 * j + 3) * NN + base];
    }
    sm4[idx] = vv;
  }
  __syncthreads();

  float m = s[0];
#pragma unroll
  for (int pp = 1; pp < 49; ++pp) m = fmaxf(m, s[pp]);
  float den = 0.f;
#pragma unroll
  for (int pp = 0; pp < 49; ++pp) {
    float e = __expf(s[pp] - m);
    s[pp] = e;
    den += e;
  }
  const float inv = 1.f / den;

  float4 y4[6];
#pragma unroll
  for (int j = 0; j < 6; ++j) y4[j] = make_float4(0.f, 0.f, 0.f, 0.f);
#pragma unroll
  for (int pp = 0; pp < 49; ++pp) {
    int dy = pp / 7, dx = pp % 7;
    int base = ((ty + dy) * 22 + (tx + dx)) * 6;
    float wgt = s[pp] * inv;
#pragma unroll
    for (int j = 0; j < 6; ++j) {
      float4 vv = sm4[base + j];
      y4[j].x = fmaf(wgt, vv.x, y4[j].x);
      y4[j].y = fmaf(wgt, vv.y, y4[j].y);
      y4[j].z = fmaf(wgt, vv.z, y4[j].z);
      y4[j].w = fmaf(wgt, vv.w, y4[j].w);
    }
  }

  const float* a = ab;
  const float* b = ab + 24 * NN;
#pragma unroll
  for (int j = 0; j < 6; ++j) {
    out[(4 * j + 0) * NN + p] = y4[j].x + a[(4 * j + 0) * NN + p];
    out[(4 * j + 1) * NN + p] = y4[j].y + a[(4 * j + 1) * NN + p];
    out[(4 * j + 2) * NN + p] = y4[j].z + a[(4 * j + 2) * NN + p];
    out[(4 * j + 3) * NN + p] = y4[j].w + a[(4 * j + 3) * NN + p];
  }
#pragma unroll
  for (int c = 0; c < 24; ++c)
    out[(24 + c) * NN + p] = b[c * NN + p];
}

// ---------------------------------------------------------------------------
extern "C" void kernel_launch(void* const* d_in, const int* in_sizes, int n_in,
                              void* d_out, int out_size, void* d_ws,
                              size_t ws_size, hipStream_t stream) {
  const float* x = (const float*)d_in[0];
  const float* w0 = (const float*)d_in[1];
  const float* b0 = (const float*)d_in[2];
  const float* w1 = (const float*)d_in[3];
  const float* b1 = (const float*)d_in[4];
  const float* w2 = (const float*)d_in[5];
  const float* b2 = (const float*)d_in[6];
  const float* w3 = (const float*)d_in[7];
  const float* b3 = (const float*)d_in[8];
  const float* sw = (const float*)d_in[9];
  const float* sb = (const float*)d_in[10];
  const float* qw = (const float*)d_in[11];
  const float* qb = (const float*)d_in[12];
  const float* kw = (const float*)d_in[13];
  const float* kb = (const float*)d_in[14];
  const float* vw = (const float*)d_in[15];
  const float* vb = (const float*)d_in[16];
  float* out = (float*)d_out;
  float* ws = (float*)d_ws;

  // workspace layout (floats):
  float* t0 = ws;                 // 2*48*NN
  float* t1 = ws + 2 * 48 * NN;   // 2*48*NN
  float* AB = ws + 4 * 48 * NN;   // 2*24*NN (a then b) — written by skip_add
  // Repacked weights live in the AB region: they're only needed during the
  // conv chain, which completes before skip_add writes AB (same stream).
  float* WR = AB;                 // 147*512 floats
  float* wr0 = WR;
  float* wr1 = WR + 3 * 512;
  float* wr2 = WR + 51 * 512;
  float* wr3 = WR + 99 * 512;
  // after the conv chain t0 is dead -> reuse for Q/K/V maps (24*NN each)
  float* Qb = t0;
  float* Kb = t0 + 24 * NN;
  float* Vb = t0 + 48 * NN;

  repack_weights<<<dim3(147), dim3(256), 0, stream>>>(w0, w1, w2, w3, WR);

  dim3 cgrd(16, 16, 2);  // z = {xa, xb} streams, shared weights
  const int smem3 = 3 * 324 * 4;
  const int smem48 = 24 * 324 * 4;

  conv3x3_v2<3, 48><<<cgrd, dim3(512), smem3, stream>>>(x, wr0, b0, t0);
  conv3x3_v2<48, 48><<<cgrd, dim3(512), smem48, stream>>>(t0, wr1, b1, t1);
  conv3x3_v2<48, 48><<<cgrd, dim3(512), smem48, stream>>>(t1, wr2, b2, t0);
  conv3x3_v2<48, 24><<<cgrd, dim3(512), smem48, stream>>>(t0, wr3, b3, t1);

  skip_add_kernel<<<dim3(256, 2), dim3(256), 0, stream>>>(t1, x, sw, sb, AB);

  qkv_kernel<<<dim3(256), dim3(256), 0, stream>>>(AB, AB + 24 * NN, qw, qb, kw,
                                                  kb, vw, vb, Qb, Kb, Vb);

  attn_kernel<<<dim3(16, 16), dim3(16, 16), 22 * 22 * 6 * 16, stream>>>(
      Qb, Kb, Vb, AB, out);
}

// Round 4
// 368.842 us; speedup vs baseline: 3.7360x; 1.3359x over previous
//
#include <hip/hip_runtime.h>
#include <math.h>

#define HH 256
#define WW 256
#define NN (HH * WW)

// ---------------------------------------------------------------------------
// Restructured direct 3x3 conv + ReLU.
// Block = 512 threads = 8 waves. Wave w owns co-group [w*CPW, (w+1)*CPW).
// Each thread computes 4 vertically adjacent pixels of a 16x16 tile, so a
// 6x3 patch (18 LDS reads) feeds CPW*9*4 FMAs per input channel, and each
// weight value (uniform per wave -> SGPR) feeds 4 FMAs.
// Input staged in LDS in <=24-channel halves (31 KB -> 2 blocks/CU, 16 waves).
// Weights come pre-repacked into 64-float aligned slices per (ci, wave) so
// the 54 (or 27) scalar loads batch into s_load_dwordx16 runs with ONE
// lgkmcnt drain per 432-cycle FMA block (R2 failure: drain every 72 cyc).
// ---------------------------------------------------------------------------
template <int CIN, int COUT>
__global__ __launch_bounds__(512, 4) void conv3x3_v2(
    const float* __restrict__ in, const float* __restrict__ wr,
    const float* __restrict__ bias, float* __restrict__ out) {
  constexpr int HALF = (CIN >= 24) ? 24 : CIN;  // channels per LDS stage
  constexpr int NH = CIN / HALF;
  constexpr int CPW = COUT / 8;  // co per wave: 6 (COUT=48) or 3 (COUT=24)
  constexpr int TT = 18 * 18;
  extern __shared__ float tile[];  // HALF * TT floats

  const int tid = threadIdx.x;
  const int wg = __builtin_amdgcn_readfirstlane(tid >> 6);  // wave-uniform
  const int s = tid & 63;
  const int x = s & 15;
  const int y0 = (s >> 4) * 4;  // 4 vertical pixels y0..y0+3
  const int bx = blockIdx.x * 16, by = blockIdx.y * 16;
  const float* inz = in + (size_t)blockIdx.z * CIN * NN;
  float* outz = out + (size_t)blockIdx.z * COUT * NN;

  float acc[CPW][4];
#pragma unroll
  for (int c = 0; c < CPW; ++c) {
    const float b = bias[wg * CPW + c];
#pragma unroll
    for (int i = 0; i < 4; ++i) acc[c][i] = b;
  }

  for (int h = 0; h < NH; ++h) {
    // ---- stage channels [h*HALF, h*HALF+HALF) into LDS
    for (int idx = tid; idx < HALF * TT; idx += 512) {
      int cl = idx / TT;
      int rem = idx - cl * TT;
      int yy = rem / 18, xx = rem - yy * 18;
      int gy = by + yy - 1, gx = bx + xx - 1;
      float v = 0.f;
      if (gy >= 0 && gy < HH && gx >= 0 && gx < WW)
        v = inz[(h * HALF + cl) * NN + gy * WW + gx];
      tile[idx] = v;
    }
    __syncthreads();

#pragma unroll 1  // keep weight SGPR footprint = one ci-step (54 floats)
    for (int ci = 0; ci < HALF; ++ci) {
      float pr[6][3];  // rows y0..y0+5, cols x..x+2 (banks: 2-way = free)
      const float* tp = tile + ci * TT + y0 * 18 + x;
#pragma unroll
      for (int r = 0; r < 6; ++r)
#pragma unroll
        for (int c = 0; c < 3; ++c) pr[r][c] = tp[r * 18 + c];

      const float* wp = wr + ((h * HALF + ci) * 8 + wg) * 64;  // 256B aligned
#pragma unroll
      for (int c = 0; c < CPW; ++c)
#pragma unroll
        for (int dy = 0; dy < 3; ++dy)
#pragma unroll
          for (int dx = 0; dx < 3; ++dx) {
            const float wv = wp[c * 9 + dy * 3 + dx];
#pragma unroll
            for (int i = 0; i < 4; ++i)
              acc[c][i] = fmaf(pr[dy + i][dx], wv, acc[c][i]);
          }
    }
    __syncthreads();
  }

  const int px = bx + x;
#pragma unroll
  for (int c = 0; c < CPW; ++c) {
    const int co = wg * CPW + c;
#pragma unroll
    for (int i = 0; i < 4; ++i)
      outz[co * NN + (by + y0 + i) * WW + px] = fmaxf(acc[c][i], 0.f);
  }
}

// ---------------------------------------------------------------------------
// Repack conv weights [COUT][CIN][3][3] -> per (ci-step, wave) slices of 64
// floats: wr[(step*8 + wg)*64 + cj*9 + k] = w[(wg*CPW+cj)][step][k].
// steps: layer0 3, layers1-3 48 each -> 147 slices * 512 floats.
// ---------------------------------------------------------------------------
__global__ __launch_bounds__(256) void repack_weights(
    const float* __restrict__ w0, const float* __restrict__ w1,
    const float* __restrict__ w2, const float* __restrict__ w3,
    float* __restrict__ wr) {
  const int b = blockIdx.x;  // 0..146 = one (layer, ci-step)
  const float* src;
  float* dst;
  int CINl, CPW, step;
  if (b < 3) {
    src = w0; dst = wr; CINl = 3; CPW = 6; step = b;
  } else if (b < 51) {
    src = w1; dst = wr + 3 * 512; CINl = 48; CPW = 6; step = b - 3;
  } else if (b < 99) {
    src = w2; dst = wr + 51 * 512; CINl = 48; CPW = 6; step = b - 51;
  } else {
    src = w3; dst = wr + 99 * 512; CINl = 48; CPW = 3; step = b - 99;
  }
  dst += step * 512;
  const int tot = 8 * CPW * 9;
  for (int e = threadIdx.x; e < tot; e += 256) {
    int wgrp = e / (CPW * 9);
    int r = e - wgrp * (CPW * 9);
    int cj = r / 9, kk = r - cj * 9;
    int co = wgrp * CPW + cj;
    dst[wgrp * 64 + cj * 9 + kk] = src[(co * CINl + step) * 9 + kk];
  }
}

// ---------------------------------------------------------------------------
// a/b = relu4_out + 1x1 skip conv of the 3-channel input. blockIdx.y = stream.
// ---------------------------------------------------------------------------
__global__ __launch_bounds__(256) void skip_add_kernel(
    const float* __restrict__ t, const float* __restrict__ x,
    const float* __restrict__ sw, const float* __restrict__ sb,
    float* __restrict__ out) {
  const int z = blockIdx.y;
  const int p = blockIdx.x * 256 + threadIdx.x;
  const float* tz = t + (size_t)z * 24 * NN;
  const float* xz = x + (size_t)z * 3 * NN;
  float* oz = out + (size_t)z * 24 * NN;
  const float x0 = xz[p], x1 = xz[NN + p], x2 = xz[2 * NN + p];
#pragma unroll
  for (int co = 0; co < 24; ++co) {
    float s = sb[co];
    s = fmaf(x0, sw[co * 3 + 0], s);
    s = fmaf(x1, sw[co * 3 + 1], s);
    s = fmaf(x2, sw[co * 3 + 2], s);
    oz[co * NN + p] = tz[co * NN + p] + s;
  }
}

// ---------------------------------------------------------------------------
// Q = 1x1(b), Kmap = 1x1(a), Vmap = 1x1(a). One thread per pixel.
// ---------------------------------------------------------------------------
__global__ __launch_bounds__(256) void qkv_kernel(
    const float* __restrict__ a, const float* __restrict__ b,
    const float* __restrict__ qw, const float* __restrict__ qb,
    const float* __restrict__ kw, const float* __restrict__ kb,
    const float* __restrict__ vw, const float* __restrict__ vb,
    float* __restrict__ Q, float* __restrict__ K, float* __restrict__ V) {
  const int p = blockIdx.x * 256 + threadIdx.x;
  float av[24], bv[24];
#pragma unroll
  for (int c = 0; c < 24; ++c) {
    av[c] = a[c * NN + p];
    bv[c] = b[c * NN + p];
  }
#pragma unroll
  for (int co = 0; co < 24; ++co) {
    float sq = qb[co], sk = kb[co], sv = vb[co];
#pragma unroll
    for (int ci = 0; ci < 24; ++ci) {
      sq = fmaf(bv[ci], qw[co * 24 + ci], sq);
      sk = fmaf(av[ci], kw[co * 24 + ci], sk);
      sv = fmaf(av[ci], vw[co * 24 + ci], sv);
    }
    Q[co * NN + p] = sq;
    K[co * NN + p] = sk;
    V[co * NN + p] = sv;
  }
}

// ---------------------------------------------------------------------------
// 7x7 local attention. 16x16 pixel tile/block; K then V staged (zero-padded)
// into one 22x22x24 LDS buffer laid out [y][x][float4-channel].
// Zero-padded K gives score 0 at borders (matches reference unfold+softmax).
// R3 fix: VGPR cap (256,3) — R3 spilled 330 MB of scratch because the fully
// unrolled 49x6 ds_read loops let the scheduler hoist loads past 256 VGPRs.
// True live set is only ~80 floats; softmax moved BEFORE V staging so only
// the 49 pre-scaled weights are live across the V barrier (q4 dead).
// s[49] must stay fully unrolled (runtime index -> scratch).
// ---------------------------------------------------------------------------
__global__ __launch_bounds__(256, 3) void attn_kernel(
    const float* __restrict__ Qm, const float* __restrict__ Km,
    const float* __restrict__ Vm, const float* __restrict__ ab,
    float* __restrict__ out) {
  extern __shared__ float4 sm4[];  // 22*22*6 float4 = 46464 B
  const int tx = threadIdx.x, ty = threadIdx.y;
  const int bx = blockIdx.x * 16, by = blockIdx.y * 16;
  const int tid = ty * 16 + tx;
  const int TOT = 22 * 22 * 6;

  // ---- stage K tile
  for (int idx = tid; idx < TOT; idx += 256) {
    int j = idx % 6;
    int pix = idx / 6;
    int xx = pix % 22, yy = pix / 22;
    int gy = by + yy - 3, gx = bx + xx - 3;
    float4 kk = make_float4(0.f, 0.f, 0.f, 0.f);
    if (gy >= 0 && gy < HH && gx >= 0 && gx < WW) {
      int base = gy * WW + gx;
      kk.x = Km[(4 * j + 0) * NN + base];
      kk.y = Km[(4 * j + 1) * NN + base];
      kk.z = Km[(4 * j + 2) * NN + base];
      kk.w = Km[(4 * j + 3) * NN + base];
    }
    sm4[idx] = kk;
  }
  __syncthreads();

  const int p = (by + ty) * WW + (bx + tx);
  float4 q4[6];
#pragma unroll
  for (int j = 0; j < 6; ++j) {
    q4[j].x = Qm[(4 * j + 0) * NN + p];
    q4[j].y = Qm[(4 * j + 1) * NN + p];
    q4[j].z = Qm[(4 * j + 2) * NN + p];
    q4[j].w = Qm[(4 * j + 3) * NN + p];
  }

  float s[49];
#pragma unroll
  for (int pp = 0; pp < 49; ++pp) {
    int dy = pp / 7, dx = pp % 7;
    int base = ((ty + dy) * 22 + (tx + dx)) * 6;
    float d = 0.f;
#pragma unroll
    for (int j = 0; j < 6; ++j) {
      float4 kk = sm4[base + j];
      d = fmaf(q4[j].x, kk.x, d);
      d = fmaf(q4[j].y, kk.y, d);
      d = fmaf(q4[j].z, kk.z, d);
      d = fmaf(q4[j].w, kk.w, d);
    }
    s[pp] = d * 0.20412414523193154f;  // 1/sqrt(24)
  }

  // ---- softmax over 49 positions (before V staging: q4 dies here, only
  // the 49 pre-scaled weights stay live across the barrier)
  float m = s[0];
#pragma unroll
  for (int pp = 1; pp < 49; ++pp) m = fmaxf(m, s[pp]);
  float den = 0.f;
#pragma unroll
  for (int pp = 0; pp < 49; ++pp) {
    float e = __expf(s[pp] - m);
    s[pp] = e;
    den += e;
  }
  const float inv = 1.f / den;
#pragma unroll
  for (int pp = 0; pp < 49; ++pp) s[pp] *= inv;

  __syncthreads();  // everyone done reading K

  // ---- stage V tile (reuse LDS)
  for (int idx = tid; idx < TOT; idx += 256) {
    int j = idx % 6;
    int pix = idx / 6;
    int xx = pix % 22, yy = pix / 22;
    int gy = by + yy - 3, gx = bx + xx - 3;
    float4 vv = make_float4(0.f, 0.f, 0.f, 0.f);
    if (gy >= 0 && gy < HH && gx >= 0 && gx < WW) {
      int base = gy * WW + gx;
      vv.x = Vm[(4 * j + 0) * NN + base];
      vv.y = Vm[(4 * j + 1) * NN + base];
      vv.z = Vm[(4 * j + 2) * NN + base];
      vv.w = Vm[(4 * j + 3) * NN + base];
    }
    sm4[idx] = vv;
  }
  __syncthreads();

  float4 y4[6];
#pragma unroll
  for (int j = 0; j < 6; ++j) y4[j] = make_float4(0.f, 0.f, 0.f, 0.f);
#pragma unroll
  for (int pp = 0; pp < 49; ++pp) {
    int dy = pp / 7, dx = pp % 7;
    int base = ((ty + dy) * 22 + (tx + dx)) * 6;
    const float wgt = s[pp];
#pragma unroll
    for (int j = 0; j < 6; ++j) {
      float4 vv = sm4[base + j];
      y4[j].x = fmaf(wgt, vv.x, y4[j].x);
      y4[j].y = fmaf(wgt, vv.y, y4[j].y);
      y4[j].z = fmaf(wgt, vv.z, y4[j].z);
      y4[j].w = fmaf(wgt, vv.w, y4[j].w);
    }
  }

  const float* a = ab;
  const float* b = ab + 24 * NN;
#pragma unroll
  for (int j = 0; j < 6; ++j) {
    out[(4 * j + 0) * NN + p] = y4[j].x + a[(4 * j + 0) * NN + p];
    out[(4 * j + 1) * NN + p] = y4[j].y + a[(4 * j + 1) * NN + p];
    out[(4 * j + 2) * NN + p] = y4[j].z + a[(4 * j + 2) * NN + p];
    out[(4 * j + 3) * NN + p] = y4[j].w + a[(4 * j + 3) * NN + p];
  }
#pragma unroll
  for (int c = 0; c < 24; ++c)
    out[(24 + c) * NN + p] = b[c * NN + p];
}

// ---------------------------------------------------------------------------
extern "C" void kernel_launch(void* const* d_in, const int* in_sizes, int n_in,
                              void* d_out, int out_size, void* d_ws,
                              size_t ws_size, hipStream_t stream) {
  const float* x = (const float*)d_in[0];
  const float* w0 = (const float*)d_in[1];
  const float* b0 = (const float*)d_in[2];
  const float* w1 = (const float*)d_in[3];
  const float* b1 = (const float*)d_in[4];
  const float* w2 = (const float*)d_in[5];
  const float* b2 = (const float*)d_in[6];
  const float* w3 = (const float*)d_in[7];
  const float* b3 = (const float*)d_in[8];
  const float* sw = (const float*)d_in[9];
  const float* sb = (const float*)d_in[10];
  const float* qw = (const float*)d_in[11];
  const float* qb = (const float*)d_in[12];
  const float* kw = (const float*)d_in[13];
  const float* kb = (const float*)d_in[14];
  const float* vw = (const float*)d_in[15];
  const float* vb = (const float*)d_in[16];
  float* out = (float*)d_out;
  float* ws = (float*)d_ws;

  // workspace layout (floats):
  float* t0 = ws;                 // 2*48*NN
  float* t1 = ws + 2 * 48 * NN;   // 2*48*NN
  float* AB = ws + 4 * 48 * NN;   // 2*24*NN (a then b) — written by skip_add
  // Repacked weights live in the AB region: they're only needed during the
  // conv chain, which completes before skip_add writes AB (same stream).
  float* WR = AB;                 // 147*512 floats
  float* wr0 = WR;
  float* wr1 = WR + 3 * 512;
  float* wr2 = WR + 51 * 512;
  float* wr3 = WR + 99 * 512;
  // after the conv chain t0 is dead -> reuse for Q/K/V maps (24*NN each)
  float* Qb = t0;
  float* Kb = t0 + 24 * NN;
  float* Vb = t0 + 48 * NN;

  repack_weights<<<dim3(147), dim3(256), 0, stream>>>(w0, w1, w2, w3, WR);

  dim3 cgrd(16, 16, 2);  // z = {xa, xb} streams, shared weights
  const int smem3 = 3 * 324 * 4;
  const int smem48 = 24 * 324 * 4;

  conv3x3_v2<3, 48><<<cgrd, dim3(512), smem3, stream>>>(x, wr0, b0, t0);
  conv3x3_v2<48, 48><<<cgrd, dim3(512), smem48, stream>>>(t0, wr1, b1, t1);
  conv3x3_v2<48, 48><<<cgrd, dim3(512), smem48, stream>>>(t1, wr2, b2, t0);
  conv3x3_v2<48, 24><<<cgrd, dim3(512), smem48, stream>>>(t0, wr3, b3, t1);

  skip_add_kernel<<<dim3(256, 2), dim3(256), 0, stream>>>(t1, x, sw, sb, AB);

  qkv_kernel<<<dim3(256), dim3(256), 0, stream>>>(AB, AB + 24 * NN, qw, qb, kw,
                                                  kb, vw, vb, Qb, Kb, Vb);

  attn_kernel<<<dim3(16, 16), dim3(16, 16), 22 * 22 * 6 * 16, stream>>>(
      Qb, Kb, Vb, AB, out);
}

// Round 6
// 198.012 us; speedup vs baseline: 6.9592x; 1.8627x over previous
//
#include <hip/hip_runtime.h>
#include <math.h>

#define HH 256
#define WW 256
#define NN (HH * WW)

typedef _Float16 f16;
typedef _Float16 f16x8 __attribute__((ext_vector_type(8)));
typedef _Float16 f16x4 __attribute__((ext_vector_type(4)));
typedef float f32x4 __attribute__((ext_vector_type(4)));

// ---------------------------------------------------------------------------
// x (2 streams, NCHW fp32, 3ch) -> xh NHWC fp16 4ch (c3 = 0 pad)
// ---------------------------------------------------------------------------
__global__ __launch_bounds__(256) void xh_convert(const float* __restrict__ x,
                                                  f16* __restrict__ xh) {
  int p = blockIdx.x * 256 + threadIdx.x;  // 0..2*NN-1
  int z = p >= NN;
  int q = p - z * NN;
  const float* xz = x + (size_t)z * 3 * NN;
  f16x4 v;
  v[0] = (f16)xz[q];
  v[1] = (f16)xz[NN + q];
  v[2] = (f16)xz[2 * NN + q];
  v[3] = (f16)0.f;
  *(f16x4*)(xh + (size_t)p * 4) = v;
}

// ---------------------------------------------------------------------------
// Repack conv weights into MFMA B-fragments (f16), lane-exact:
// B[k=quad*8+j][n=lane&15] for v_mfma_f32_16x16x32_f16.
// L0  (offset 0):     [nt:3][lane:64][j:8], k=quad*8+j, k<27: tap=k/3, ci=k%3
// L1/2/3:             [nt][tap:9][kc:2][lane:64][j:8], ci=kc*32+quad*8+j (<48)
// f16 offsets: O0=0, O1=1536, O2=29184, O3=56832, total 75264.
// ---------------------------------------------------------------------------
__global__ __launch_bounds__(256) void repack_frags(
    const float* __restrict__ w0, const float* __restrict__ w1,
    const float* __restrict__ w2, const float* __restrict__ w3,
    f16* __restrict__ bf) {
  const int O1 = 1536, O2 = O1 + 27648, O3 = O2 + 27648;
  int e = blockIdx.x * 256 + threadIdx.x;
  if (e >= 75264) return;
  const float* w;
  int COUT, idx, mode;
  if (e < O1)      { w = w0; COUT = 48; idx = e;      mode = 0; }
  else if (e < O2) { w = w1; COUT = 48; idx = e - O1; mode = 1; }
  else if (e < O3) { w = w2; COUT = 48; idx = e - O2; mode = 1; }
  else             { w = w3; COUT = 24; idx = e - O3; mode = 1; }
  int j = idx & 7;
  int lane = (idx >> 3) & 63;
  int rest = idx >> 9;
  int n = lane & 15, quad = lane >> 4;
  float val = 0.f;
  if (mode == 0) {
    int nt = rest;
    int k = quad * 8 + j;
    int cout = nt * 16 + n;
    if (k < 27) {
      int tap = k / 3, ci = k - tap * 3;
      val = w[(cout * 3 + ci) * 9 + tap];  // OIHW, tap = dy*3+dx
    }
  } else {
    int kc = rest & 1;
    int tap = (rest >> 1) % 9;
    int nt = (rest >> 1) / 9;
    int ci = kc * 32 + quad * 8 + j;
    int cout = nt * 16 + n;
    if (ci < 48 && cout < COUT) val = w[(cout * 48 + ci) * 9 + tap];
  }
  bf[e] = (f16)val;
}

// ---------------------------------------------------------------------------
// Layer 0: 3->48, K=27 padded to 32. Direct im2col A-panel in LDS,
// 80 B/pixel stride (bank-friendly). One MFMA per N-tile per M-row.
// Output NHWC f16 (48ch) with relu.
// ---------------------------------------------------------------------------
__global__ __launch_bounds__(256, 2) void conv0_gemm(
    const f16* __restrict__ xh, const f16* __restrict__ bf0,
    const float* __restrict__ bias, f16* __restrict__ outh) {
  extern __shared__ char smem[];  // 256*80 B
  const int tid = threadIdx.x;
  const int lane = tid & 63, wave = tid >> 6;
  const int n = lane & 15, quad = lane >> 4;
  const int bx = blockIdx.x * 16, by = blockIdx.y * 16, z = blockIdx.z;
  const f16* xz = xh + (size_t)z * NN * 4;

  {  // build this pixel's 27-wide im2col row (+5 zeros)
    int p = tid, y = p >> 4, xcol = p & 15;
    int gy = by + y, gx = bx + xcol;
    f16* row = (f16*)(smem + p * 80);
#pragma unroll
    for (int tap = 0; tap < 9; ++tap) {
      int dy = tap / 3, dx = tap - (tap / 3) * 3;
      int sy = gy + dy - 1, sx = gx + dx - 1;
      f16 c0 = (f16)0.f, c1 = c0, c2 = c0;
      if (sy >= 0 && sy < HH && sx >= 0 && sx < WW) {
        const f16* s = xz + ((size_t)sy * WW + sx) * 4;
        c0 = s[0]; c1 = s[1]; c2 = s[2];
      }
      row[tap * 3 + 0] = c0;
      row[tap * 3 + 1] = c1;
      row[tap * 3 + 2] = c2;
    }
#pragma unroll
    for (int k = 27; k < 32; ++k) row[k] = (f16)0.f;
  }
  __syncthreads();

  f32x4 acc[4][3];
#pragma unroll
  for (int nt = 0; nt < 3; ++nt) {
    float bv = bias[nt * 16 + n];
#pragma unroll
    for (int i = 0; i < 4; ++i) acc[i][nt] = (f32x4){bv, bv, bv, bv};
  }
  f16x8 B[3];
#pragma unroll
  for (int nt = 0; nt < 3; ++nt)
    B[nt] = *(const f16x8*)(bf0 + (nt * 64 + lane) * 8);
#pragma unroll
  for (int i = 0; i < 4; ++i) {
    int r = wave * 4 + i;  // M-tile = row r; A: m = lane&15
    f16x8 a = *(const f16x8*)(smem + (r * 16 + n) * 80 + quad * 16);
#pragma unroll
    for (int nt = 0; nt < 3; ++nt)
      acc[i][nt] =
          __builtin_amdgcn_mfma_f32_16x16x32_f16(a, B[nt], acc[i][nt], 0, 0, 0);
  }

  f16* oz = outh + (size_t)z * NN * 48;
#pragma unroll
  for (int i = 0; i < 4; ++i) {
    int y = by + wave * 4 + i;
#pragma unroll
    for (int nt = 0; nt < 3; ++nt)
#pragma unroll
      for (int reg = 0; reg < 4; ++reg)
        oz[((size_t)y * WW + bx + quad * 4 + reg) * 48 + nt * 16 + n] =
            (f16)fmaxf(acc[i][nt][reg], 0.f);
  }
}

// ---------------------------------------------------------------------------
// Layers 1-3: 48->COUT implicit GEMM. NHWC f16 input; 18x18 halo tile in LDS
// at 144 B/pixel (48ch + 16ch zero pad -> two K=32 chunks per tap, 2-way
// banks = free). Block = 256 thr / 4 waves = 256 px x COUT. Wave w owns rows
// 4w..4w+3; per (row, tap): 2x ds_read_b128 A-frags feed 2*NT MFMAs.
// FUSE (layer 3): epilogue adds 1x1 skip conv of x, writes fp32 planar a/b.
// ---------------------------------------------------------------------------
template <int NT, int COUT, bool FUSE>
__global__ __launch_bounds__(256, 2) void gemm_conv(
    const f16* __restrict__ in, const f16* __restrict__ bfr,
    const float* __restrict__ bias, f16* __restrict__ outh,
    float* __restrict__ outf, const float* __restrict__ xsrc,
    const float* __restrict__ skw, const float* __restrict__ skb) {
  extern __shared__ char smem[];           // 324*144 (+3KB xt if FUSE)
  float* xt = (float*)(smem + 324 * 144);  // [c:3][y:16][x:16]
  const int tid = threadIdx.x;
  const int lane = tid & 63, wave = tid >> 6;
  const int n = lane & 15, quad = lane >> 4;
  const int bx = blockIdx.x * 16, by = blockIdx.y * 16, z = blockIdx.z;
  const f16* inz = in + (size_t)z * NN * 48;

  for (int p = tid; p < 324; p += 256) {
    int yy = p / 18, xx = p - yy * 18;
    int gy = by + yy - 1, gx = bx + xx - 1;
    float4* dst = (float4*)(smem + p * 144);
    if (gy >= 0 && gy < HH && gx >= 0 && gx < WW) {
      const float4* s = (const float4*)(inz + ((size_t)gy * WW + gx) * 48);
      float4 a0 = s[0], a1 = s[1], a2 = s[2], a3 = s[3], a4 = s[4], a5 = s[5];
      dst[0] = a0; dst[1] = a1; dst[2] = a2;
      dst[3] = a3; dst[4] = a4; dst[5] = a5;
      dst[6] = make_float4(0, 0, 0, 0);
      dst[7] = make_float4(0, 0, 0, 0);
    } else {
      float4 zz = make_float4(0, 0, 0, 0);
#pragma unroll
      for (int c = 0; c < 8; ++c) dst[c] = zz;
    }
  }
  if (FUSE) {
    for (int i = tid; i < 768; i += 256) {
      int c = i >> 8, p = i & 255;
      xt[i] = xsrc[(size_t)z * 3 * NN + c * NN + (by + (p >> 4)) * WW + bx +
                   (p & 15)];
    }
  }
  __syncthreads();

  f32x4 acc[4][NT];
#pragma unroll
  for (int nt = 0; nt < NT; ++nt) {
    int cc = nt * 16 + n;
    float bv = (cc < COUT) ? bias[cc] : 0.f;
#pragma unroll
    for (int i = 0; i < 4; ++i) acc[i][nt] = (f32x4){bv, bv, bv, bv};
  }

  const int r0 = wave * 4;
#pragma unroll
  for (int tap = 0; tap < 9; ++tap) {
    const int dy = tap / 3, dx = tap - dy * 3;
    f16x8 B[2][NT];
#pragma unroll
    for (int kc = 0; kc < 2; ++kc)
#pragma unroll
      for (int nt = 0; nt < NT; ++nt)
        B[kc][nt] =
            *(const f16x8*)(bfr + (((nt * 9 + tap) * 2 + kc) * 64 + lane) * 8);
#pragma unroll
    for (int i = 0; i < 4; ++i) {
      const int p = (r0 + i + dy) * 18 + (n + dx);  // A: m = lane&15
      const char* ap = smem + p * 144;
      f16x8 a0 = *(const f16x8*)(ap + quad * 16);
      f16x8 a1 = *(const f16x8*)(ap + 64 + quad * 16);
#pragma unroll
      for (int nt = 0; nt < NT; ++nt)
        acc[i][nt] = __builtin_amdgcn_mfma_f32_16x16x32_f16(a0, B[0][nt],
                                                            acc[i][nt], 0, 0, 0);
#pragma unroll
      for (int nt = 0; nt < NT; ++nt)
        acc[i][nt] = __builtin_amdgcn_mfma_f32_16x16x32_f16(a1, B[1][nt],
                                                            acc[i][nt], 0, 0, 0);
    }
  }

  if (!FUSE) {
    f16* oz = outh + (size_t)z * NN * 48;
#pragma unroll
    for (int i = 0; i < 4; ++i) {
      int y = by + r0 + i;
#pragma unroll
      for (int nt = 0; nt < NT; ++nt)
#pragma unroll
        for (int reg = 0; reg < 4; ++reg)
          oz[((size_t)y * WW + bx + quad * 4 + reg) * 48 + nt * 16 + n] =
              (f16)fmaxf(acc[i][nt][reg], 0.f);
    }
  } else {
    float* oz = outf + (size_t)z * 24 * NN;
#pragma unroll
    for (int i = 0; i < 4; ++i) {
      int y = by + r0 + i;
#pragma unroll
      for (int nt = 0; nt < NT; ++nt) {
        int cc = nt * 16 + n;
        if (cc < 24) {
          float s0 = skw[cc * 3 + 0], s1 = skw[cc * 3 + 1],
                s2 = skw[cc * 3 + 2], sb0 = skb[cc];
          f32x4 o;
#pragma unroll
          for (int reg = 0; reg < 4; ++reg) {
            int pl = (r0 + i) * 16 + quad * 4 + reg;
            float sk = sb0 + s0 * xt[pl] + s1 * xt[256 + pl] + s2 * xt[512 + pl];
            o[reg] = fmaxf(acc[i][nt][reg], 0.f) + sk;
          }
          *(f32x4*)(oz + (size_t)cc * NN + (size_t)y * WW + bx + quad * 4) = o;
        }
      }
    }
  }
}

// ---------------------------------------------------------------------------
// Q = 1x1(b), Kmap = 1x1(a), Vmap = 1x1(a). One thread per pixel.
// ---------------------------------------------------------------------------
__global__ __launch_bounds__(256) void qkv_kernel(
    const float* __restrict__ a, const float* __restrict__ b,
    const float* __restrict__ qw, const float* __restrict__ qb,
    const float* __restrict__ kw, const float* __restrict__ kb,
    const float* __restrict__ vw, const float* __restrict__ vb,
    float* __restrict__ Q, float* __restrict__ K, float* __restrict__ V) {
  const int p = blockIdx.x * 256 + threadIdx.x;
  float av[24], bv[24];
#pragma unroll
  for (int c = 0; c < 24; ++c) {
    av[c] = a[c * NN + p];
    bv[c] = b[c * NN + p];
  }
#pragma unroll
  for (int co = 0; co < 24; ++co) {
    float sq = qb[co], sk = kb[co], sv = vb[co];
#pragma unroll
    for (int ci = 0; ci < 24; ++ci) {
      sq = fmaf(bv[ci], qw[co * 24 + ci], sq);
      sk = fmaf(av[ci], kw[co * 24 + ci], sk);
      sv = fmaf(av[ci], vw[co * 24 + ci], sv);
    }
    Q[co * NN + p] = sq;
    K[co * NN + p] = sk;
    V[co * NN + p] = sv;
  }
}

// ---------------------------------------------------------------------------
// 7x7 local attention (unchanged, spill-free).
// ---------------------------------------------------------------------------
__global__ __launch_bounds__(256, 3) void attn_kernel(
    const float* __restrict__ Qm, const float* __restrict__ Km,
    const float* __restrict__ Vm, const float* __restrict__ ab,
    float* __restrict__ out) {
  extern __shared__ float4 sm4[];  // 22*22*6 float4 = 46464 B
  const int tx = threadIdx.x, ty = threadIdx.y;
  const int bx = blockIdx.x * 16, by = blockIdx.y * 16;
  const int tid = ty * 16 + tx;
  const int TOT = 22 * 22 * 6;

  for (int idx = tid; idx < TOT; idx += 256) {
    int j = idx % 6;
    int pix = idx / 6;
    int xx = pix % 22, yy = pix / 22;
    int gy = by + yy - 3, gx = bx + xx - 3;
    float4 kk = make_float4(0.f, 0.f, 0.f, 0.f);
    if (gy >= 0 && gy < HH && gx >= 0 && gx < WW) {
      int base = gy * WW + gx;
      kk.x = Km[(4 * j + 0) * NN + base];
      kk.y = Km[(4 * j + 1) * NN + base];
      kk.z = Km[(4 * j + 2) * NN + base];
      kk.w = Km[(4 * j + 3) * NN + base];
    }
    sm4[idx] = kk;
  }
  __syncthreads();

  const int p = (by + ty) * WW + (bx + tx);
  float4 q4[6];
#pragma unroll
  for (int j = 0; j < 6; ++j) {
    q4[j].x = Qm[(4 * j + 0) * NN + p];
    q4[j].y = Qm[(4 * j + 1) * NN + p];
    q4[j].z = Qm[(4 * j + 2) * NN + p];
    q4[j].w = Qm[(4 * j + 3) * NN + p];
  }

  float s[49];
#pragma unroll
  for (int pp = 0; pp < 49; ++pp) {
    int dy = pp / 7, dx = pp % 7;
    int base = ((ty + dy) * 22 + (tx + dx)) * 6;
    float d = 0.f;
#pragma unroll
    for (int j = 0; j < 6; ++j) {
      float4 kk = sm4[base + j];
      d = fmaf(q4[j].x, kk.x, d);
      d = fmaf(q4[j].y, kk.y, d);
      d = fmaf(q4[j].z, kk.z, d);
      d = fmaf(q4[j].w, kk.w, d);
    }
    s[pp] = d * 0.20412414523193154f;  // 1/sqrt(24)
  }

  float m = s[0];
#pragma unroll
  for (int pp = 1; pp < 49; ++pp) m = fmaxf(m, s[pp]);
  float den = 0.f;
#pragma unroll
  for (int pp = 0; pp < 49; ++pp) {
    float e = __expf(s[pp] - m);
    s[pp] = e;
    den += e;
  }
  const float inv = 1.f / den;
#pragma unroll
  for (int pp = 0; pp < 49; ++pp) s[pp] *= inv;

  __syncthreads();

  for (int idx = tid; idx < TOT; idx += 256) {
    int j = idx % 6;
    int pix = idx / 6;
    int xx = pix % 22, yy = pix / 22;
    int gy = by + yy - 3, gx = bx + xx - 3;
    float4 vv = make_float4(0.f, 0.f, 0.f, 0.f);
    if (gy >= 0 && gy < HH && gx >= 0 && gx < WW) {
      int base = gy * WW + gx;
      vv.x = Vm[(4 * j + 0) * NN + base];
      vv.y = Vm[(4 * j + 1) * NN + base];
      vv.z = Vm[(4 * j + 2) * NN + base];
      vv.w = Vm[(4 * j + 3) * NN + base];
    }
    sm4[idx] = vv;
  }
  __syncthreads();

  float4 y4[6];
#pragma unroll
  for (int j = 0; j < 6; ++j) y4[j] = make_float4(0.f, 0.f, 0.f, 0.f);
#pragma unroll
  for (int pp = 0; pp < 49; ++pp) {
    int dy = pp / 7, dx = pp % 7;
    int base = ((ty + dy) * 22 + (tx + dx)) * 6;
    const float wgt = s[pp];
#pragma unroll
    for (int j = 0; j < 6; ++j) {
      float4 vv = sm4[base + j];
      y4[j].x = fmaf(wgt, vv.x, y4[j].x);
      y4[j].y = fmaf(wgt, vv.y, y4[j].y);
      y4[j].z = fmaf(wgt, vv.z, y4[j].z);
      y4[j].w = fmaf(wgt, vv.w, y4[j].w);
    }
  }

  const float* a = ab;
  const float* b = ab + 24 * NN;
#pragma unroll
  for (int j = 0; j < 6; ++j) {
    out[(4 * j + 0) * NN + p] = y4[j].x + a[(4 * j + 0) * NN + p];
    out[(4 * j + 1) * NN + p] = y4[j].y + a[(4 * j + 1) * NN + p];
    out[(4 * j + 2) * NN + p] = y4[j].z + a[(4 * j + 2) * NN + p];
    out[(4 * j + 3) * NN + p] = y4[j].w + a[(4 * j + 3) * NN + p];
  }
#pragma unroll
  for (int c = 0; c < 24; ++c)
    out[(24 + c) * NN + p] = b[c * NN + p];
}

// ---------------------------------------------------------------------------
extern "C" void kernel_launch(void* const* d_in, const int* in_sizes, int n_in,
                              void* d_out, int out_size, void* d_ws,
                              size_t ws_size, hipStream_t stream) {
  const float* x = (const float*)d_in[0];
  const float* w0 = (const float*)d_in[1];
  const float* b0 = (const float*)d_in[2];
  const float* w1 = (const float*)d_in[3];
  const float* b1 = (const float*)d_in[4];
  const float* w2 = (const float*)d_in[5];
  const float* b2 = (const float*)d_in[6];
  const float* w3 = (const float*)d_in[7];
  const float* b3 = (const float*)d_in[8];
  const float* sw = (const float*)d_in[9];
  const float* sb = (const float*)d_in[10];
  const float* qw = (const float*)d_in[11];
  const float* qb = (const float*)d_in[12];
  const float* kw = (const float*)d_in[13];
  const float* kb = (const float*)d_in[14];
  const float* vw = (const float*)d_in[15];
  const float* vb = (const float*)d_in[16];
  float* out = (float*)d_out;
  float* ws = (float*)d_ws;

  // workspace layout (float units):
  // R5 BUG: XH is 2*NN*4 f16 = 4*NN floats, but BF was placed at +2*NN ->
  // repack_frags clobbered stream-b pixels 0..18824 of XH. Fixed: BF at 220.
  float* AB = ws;                        // 48*NN  (a then b, fp32 planar)
  float* Qb = ws + (size_t)48 * NN;      // 24*NN
  float* Kb = ws + (size_t)72 * NN;      // 24*NN
  float* Vb = ws + (size_t)96 * NN;      // 24*NN
  f16* ACT0 = (f16*)(ws + (size_t)120 * NN);  // 2*NN*48 f16 = 48*NN floats
  f16* ACT1 = (f16*)(ws + (size_t)168 * NN);  // 48*NN floats
  f16* XH = (f16*)(ws + (size_t)216 * NN);    // 2*NN*4 f16 = 4*NN floats
  f16* BF = (f16*)(ws + (size_t)220 * NN);    // 75264 f16

  xh_convert<<<dim3(512), dim3(256), 0, stream>>>(x, XH);
  repack_frags<<<dim3(294), dim3(256), 0, stream>>>(w0, w1, w2, w3, BF);

  dim3 cgrd(16, 16, 2);
  conv0_gemm<<<cgrd, dim3(256), 256 * 80, stream>>>(XH, BF, b0, ACT0);
  gemm_conv<3, 48, false><<<cgrd, dim3(256), 324 * 144, stream>>>(
      ACT0, BF + 1536, b1, ACT1, nullptr, nullptr, nullptr, nullptr);
  gemm_conv<3, 48, false><<<cgrd, dim3(256), 324 * 144, stream>>>(
      ACT1, BF + 29184, b2, ACT0, nullptr, nullptr, nullptr, nullptr);
  gemm_conv<2, 24, true><<<cgrd, dim3(256), 324 * 144 + 3072, stream>>>(
      ACT0, BF + 56832, b3, nullptr, AB, x, sw, sb);

  qkv_kernel<<<dim3(256), dim3(256), 0, stream>>>(AB, AB + 24 * NN, qw, qb, kw,
                                                  kb, vw, vb, Qb, Kb, Vb);

  attn_kernel<<<dim3(16, 16), dim3(16, 16), 22 * 22 * 6 * 16, stream>>>(
      Qb, Kb, Vb, AB, out);
}

// Round 7
// 184.950 us; speedup vs baseline: 7.4507x; 1.0706x over previous
//
#include <hip/hip_runtime.h>
#include <math.h>

#define HH 256
#define WW 256
#define NN (HH * WW)

typedef _Float16 f16;
typedef _Float16 f16x8 __attribute__((ext_vector_type(8)));
typedef _Float16 f16x4 __attribute__((ext_vector_type(4)));
typedef _Float16 f16x2 __attribute__((ext_vector_type(2)));
typedef float f32x4 __attribute__((ext_vector_type(4)));

// ---------------------------------------------------------------------------
// x (2 streams, NCHW fp32, 3ch) -> xh NHWC fp16 4ch (c3 = 0 pad)
// ---------------------------------------------------------------------------
__global__ __launch_bounds__(256) void xh_convert(const float* __restrict__ x,
                                                  f16* __restrict__ xh) {
  int p = blockIdx.x * 256 + threadIdx.x;  // 0..2*NN-1
  int z = p >= NN;
  int q = p - z * NN;
  const float* xz = x + (size_t)z * 3 * NN;
  f16x4 v;
  v[0] = (f16)xz[q];
  v[1] = (f16)xz[NN + q];
  v[2] = (f16)xz[2 * NN + q];
  v[3] = (f16)0.f;
  *(f16x4*)(xh + (size_t)p * 4) = v;
}

// ---------------------------------------------------------------------------
// Repack conv weights into MFMA B-fragments (f16), lane-exact:
// B[k=quad*8+j][n=lane&15] for v_mfma_f32_16x16x32_f16.
// ---------------------------------------------------------------------------
__global__ __launch_bounds__(256) void repack_frags(
    const float* __restrict__ w0, const float* __restrict__ w1,
    const float* __restrict__ w2, const float* __restrict__ w3,
    f16* __restrict__ bf) {
  const int O1 = 1536, O2 = O1 + 27648, O3 = O2 + 27648;
  int e = blockIdx.x * 256 + threadIdx.x;
  if (e >= 75264) return;
  const float* w;
  int COUT, idx, mode;
  if (e < O1)      { w = w0; COUT = 48; idx = e;      mode = 0; }
  else if (e < O2) { w = w1; COUT = 48; idx = e - O1; mode = 1; }
  else if (e < O3) { w = w2; COUT = 48; idx = e - O2; mode = 1; }
  else             { w = w3; COUT = 24; idx = e - O3; mode = 1; }
  int j = idx & 7;
  int lane = (idx >> 3) & 63;
  int rest = idx >> 9;
  int n = lane & 15, quad = lane >> 4;
  float val = 0.f;
  if (mode == 0) {
    int nt = rest;
    int k = quad * 8 + j;
    int cout = nt * 16 + n;
    if (k < 27) {
      int tap = k / 3, ci = k - tap * 3;
      val = w[(cout * 3 + ci) * 9 + tap];  // OIHW, tap = dy*3+dx
    }
  } else {
    int kc = rest & 1;
    int tap = (rest >> 1) % 9;
    int nt = (rest >> 1) / 9;
    int ci = kc * 32 + quad * 8 + j;
    int cout = nt * 16 + n;
    if (ci < 48 && cout < COUT) val = w[(cout * 48 + ci) * 9 + tap];
  }
  bf[e] = (f16)val;
}

// ---------------------------------------------------------------------------
// Layer 0: 3->48, K=27 padded to 32. Direct im2col A-panel in LDS.
// ---------------------------------------------------------------------------
__global__ __launch_bounds__(256, 2) void conv0_gemm(
    const f16* __restrict__ xh, const f16* __restrict__ bf0,
    const float* __restrict__ bias, f16* __restrict__ outh) {
  extern __shared__ char smem[];  // 256*80 B
  const int tid = threadIdx.x;
  const int lane = tid & 63, wave = tid >> 6;
  const int n = lane & 15, quad = lane >> 4;
  const int bx = blockIdx.x * 16, by = blockIdx.y * 16, z = blockIdx.z;
  const f16* xz = xh + (size_t)z * NN * 4;

  {
    int p = tid, y = p >> 4, xcol = p & 15;
    int gy = by + y, gx = bx + xcol;
    f16* row = (f16*)(smem + p * 80);
#pragma unroll
    for (int tap = 0; tap < 9; ++tap) {
      int dy = tap / 3, dx = tap - (tap / 3) * 3;
      int sy = gy + dy - 1, sx = gx + dx - 1;
      f16 c0 = (f16)0.f, c1 = c0, c2 = c0;
      if (sy >= 0 && sy < HH && sx >= 0 && sx < WW) {
        const f16* s = xz + ((size_t)sy * WW + sx) * 4;
        c0 = s[0]; c1 = s[1]; c2 = s[2];
      }
      row[tap * 3 + 0] = c0;
      row[tap * 3 + 1] = c1;
      row[tap * 3 + 2] = c2;
    }
#pragma unroll
    for (int k = 27; k < 32; ++k) row[k] = (f16)0.f;
  }
  __syncthreads();

  f32x4 acc[4][3];
#pragma unroll
  for (int nt = 0; nt < 3; ++nt) {
    float bv = bias[nt * 16 + n];
#pragma unroll
    for (int i = 0; i < 4; ++i) acc[i][nt] = (f32x4){bv, bv, bv, bv};
  }
  f16x8 B[3];
#pragma unroll
  for (int nt = 0; nt < 3; ++nt)
    B[nt] = *(const f16x8*)(bf0 + (nt * 64 + lane) * 8);
#pragma unroll
  for (int i = 0; i < 4; ++i) {
    int r = wave * 4 + i;
    f16x8 a = *(const f16x8*)(smem + (r * 16 + n) * 80 + quad * 16);
#pragma unroll
    for (int nt = 0; nt < 3; ++nt)
      acc[i][nt] =
          __builtin_amdgcn_mfma_f32_16x16x32_f16(a, B[nt], acc[i][nt], 0, 0, 0);
  }

  f16* oz = outh + (size_t)z * NN * 48;
#pragma unroll
  for (int i = 0; i < 4; ++i) {
    int y = by + wave * 4 + i;
#pragma unroll
    for (int nt = 0; nt < 3; ++nt)
#pragma unroll
      for (int reg = 0; reg < 4; ++reg)
        oz[((size_t)y * WW + bx + quad * 4 + reg) * 48 + nt * 16 + n] =
            (f16)fmaxf(acc[i][nt][reg], 0.f);
  }
}

// ---------------------------------------------------------------------------
// Layers 1-3: 48->COUT implicit GEMM (unchanged from R6).
// ---------------------------------------------------------------------------
template <int NT, int COUT, bool FUSE>
__global__ __launch_bounds__(256, 2) void gemm_conv(
    const f16* __restrict__ in, const f16* __restrict__ bfr,
    const float* __restrict__ bias, f16* __restrict__ outh,
    float* __restrict__ outf, const float* __restrict__ xsrc,
    const float* __restrict__ skw, const float* __restrict__ skb) {
  extern __shared__ char smem[];           // 324*144 (+3KB xt if FUSE)
  float* xt = (float*)(smem + 324 * 144);  // [c:3][y:16][x:16]
  const int tid = threadIdx.x;
  const int lane = tid & 63, wave = tid >> 6;
  const int n = lane & 15, quad = lane >> 4;
  const int bx = blockIdx.x * 16, by = blockIdx.y * 16, z = blockIdx.z;
  const f16* inz = in + (size_t)z * NN * 48;

  for (int p = tid; p < 324; p += 256) {
    int yy = p / 18, xx = p - yy * 18;
    int gy = by + yy - 1, gx = bx + xx - 1;
    float4* dst = (float4*)(smem + p * 144);
    if (gy >= 0 && gy < HH && gx >= 0 && gx < WW) {
      const float4* s = (const float4*)(inz + ((size_t)gy * WW + gx) * 48);
      float4 a0 = s[0], a1 = s[1], a2 = s[2], a3 = s[3], a4 = s[4], a5 = s[5];
      dst[0] = a0; dst[1] = a1; dst[2] = a2;
      dst[3] = a3; dst[4] = a4; dst[5] = a5;
      dst[6] = make_float4(0, 0, 0, 0);
      dst[7] = make_float4(0, 0, 0, 0);
    } else {
      float4 zz = make_float4(0, 0, 0, 0);
#pragma unroll
      for (int c = 0; c < 8; ++c) dst[c] = zz;
    }
  }
  if (FUSE) {
    for (int i = tid; i < 768; i += 256) {
      int c = i >> 8, p = i & 255;
      xt[i] = xsrc[(size_t)z * 3 * NN + c * NN + (by + (p >> 4)) * WW + bx +
                   (p & 15)];
    }
  }
  __syncthreads();

  f32x4 acc[4][NT];
#pragma unroll
  for (int nt = 0; nt < NT; ++nt) {
    int cc = nt * 16 + n;
    float bv = (cc < COUT) ? bias[cc] : 0.f;
#pragma unroll
    for (int i = 0; i < 4; ++i) acc[i][nt] = (f32x4){bv, bv, bv, bv};
  }

  const int r0 = wave * 4;
#pragma unroll
  for (int tap = 0; tap < 9; ++tap) {
    const int dy = tap / 3, dx = tap - dy * 3;
    f16x8 B[2][NT];
#pragma unroll
    for (int kc = 0; kc < 2; ++kc)
#pragma unroll
      for (int nt = 0; nt < NT; ++nt)
        B[kc][nt] =
            *(const f16x8*)(bfr + (((nt * 9 + tap) * 2 + kc) * 64 + lane) * 8);
#pragma unroll
    for (int i = 0; i < 4; ++i) {
      const int p = (r0 + i + dy) * 18 + (n + dx);
      const char* ap = smem + p * 144;
      f16x8 a0 = *(const f16x8*)(ap + quad * 16);
      f16x8 a1 = *(const f16x8*)(ap + 64 + quad * 16);
#pragma unroll
      for (int nt = 0; nt < NT; ++nt)
        acc[i][nt] = __builtin_amdgcn_mfma_f32_16x16x32_f16(a0, B[0][nt],
                                                            acc[i][nt], 0, 0, 0);
#pragma unroll
      for (int nt = 0; nt < NT; ++nt)
        acc[i][nt] = __builtin_amdgcn_mfma_f32_16x16x32_f16(a1, B[1][nt],
                                                            acc[i][nt], 0, 0, 0);
    }
  }

  if (!FUSE) {
    f16* oz = outh + (size_t)z * NN * 48;
#pragma unroll
    for (int i = 0; i < 4; ++i) {
      int y = by + r0 + i;
#pragma unroll
      for (int nt = 0; nt < NT; ++nt)
#pragma unroll
        for (int reg = 0; reg < 4; ++reg)
          oz[((size_t)y * WW + bx + quad * 4 + reg) * 48 + nt * 16 + n] =
              (f16)fmaxf(acc[i][nt][reg], 0.f);
    }
  } else {
    float* oz = outf + (size_t)z * 24 * NN;
#pragma unroll
    for (int i = 0; i < 4; ++i) {
      int y = by + r0 + i;
#pragma unroll
      for (int nt = 0; nt < NT; ++nt) {
        int cc = nt * 16 + n;
        if (cc < 24) {
          float s0 = skw[cc * 3 + 0], s1 = skw[cc * 3 + 1],
                s2 = skw[cc * 3 + 2], sb0 = skb[cc];
          f32x4 o;
#pragma unroll
          for (int reg = 0; reg < 4; ++reg) {
            int pl = (r0 + i) * 16 + quad * 4 + reg;
            float sk = sb0 + s0 * xt[pl] + s1 * xt[256 + pl] + s2 * xt[512 + pl];
            o[reg] = fmaxf(acc[i][nt][reg], 0.f) + sk;
          }
          *(f32x4*)(oz + (size_t)cc * NN + (size_t)y * WW + bx + quad * 4) = o;
        }
      }
    }
  }
}

// ---------------------------------------------------------------------------
// QKV v2: reads a/b (fp32 planar), writes Qh = NHWC f16 (24ch, 48B/px) and
// KVh = interleaved NHWC f16 (K 24ch + V 24ch, 96B/px) for contiguous attn
// staging. Compute stays fp32.
// ---------------------------------------------------------------------------
__global__ __launch_bounds__(256) void qkv_kernel(
    const float* __restrict__ a, const float* __restrict__ b,
    const float* __restrict__ qw, const float* __restrict__ qb,
    const float* __restrict__ kw, const float* __restrict__ kb,
    const float* __restrict__ vw, const float* __restrict__ vb,
    f16* __restrict__ Qh, f16* __restrict__ KVh) {
  const int p = blockIdx.x * 256 + threadIdx.x;
  float av[24], bv[24];
#pragma unroll
  for (int c = 0; c < 24; ++c) {
    av[c] = a[c * NN + p];
    bv[c] = b[c * NN + p];
  }
  f16 qo[24], ko[24], vo[24];
#pragma unroll
  for (int co = 0; co < 24; ++co) {
    float sq = qb[co], sk = kb[co], sv = vb[co];
#pragma unroll
    for (int ci = 0; ci < 24; ++ci) {
      sq = fmaf(bv[ci], qw[co * 24 + ci], sq);
      sk = fmaf(av[ci], kw[co * 24 + ci], sk);
      sv = fmaf(av[ci], vw[co * 24 + ci], sv);
    }
    qo[co] = (f16)sq;
    ko[co] = (f16)sk;
    vo[co] = (f16)sv;
  }
#pragma unroll
  for (int t = 0; t < 3; ++t)
    *(f16x8*)(Qh + (size_t)p * 24 + t * 8) = *(f16x8*)(qo + t * 8);
#pragma unroll
  for (int t = 0; t < 3; ++t)
    *(f16x8*)(KVh + (size_t)p * 48 + t * 8) = *(f16x8*)(ko + t * 8);
#pragma unroll
  for (int t = 0; t < 3; ++t)
    *(f16x8*)(KVh + (size_t)p * 48 + 24 + t * 8) = *(f16x8*)(vo + t * 8);
}

// ---------------------------------------------------------------------------
// Attention v2. 32x8 px tile / 256 threads (1 px/thread), grid (8,32).
// Single LDS stage: 38x14 halo, 112B/px slot (K 48B | V 48B | 16B pad).
// 112B = 28-dword stride -> 8 consecutive lanes tile all 32 banks:
// conflict-free ds_read_b128. 32-wide tiles -> all global reads/writes are
// full 128B lines (R6: 16-wide tiles caused 2x write amplification).
// Scores: v_dot2_f32_f16 (f32 accum). PV: v_pk_fma_f16 (f16 accum; softmax
// weights sum to 1 so abs error ~1e-2, fine vs 0.19 threshold).
// ---------------------------------------------------------------------------
__device__ inline float dot8(f16x8 a, f16x8 b, float acc) {
#if __has_builtin(__builtin_amdgcn_fdot2)
#pragma unroll
  for (int i = 0; i < 4; ++i)
    acc = __builtin_amdgcn_fdot2(
        __builtin_shufflevector(a, a, 0, 1) /*placeholder*/,
        __builtin_shufflevector(b, b, 0, 1), acc, false);
  // NOTE: placeholder above replaced below by explicit pairs
  return acc;
#else
#pragma unroll
  for (int i = 0; i < 8; ++i) acc += (float)a[i] * (float)b[i];
  return acc;
#endif
}

__device__ inline float dot8p(f16x8 a, f16x8 b, float acc) {
#if __has_builtin(__builtin_amdgcn_fdot2)
  acc = __builtin_amdgcn_fdot2(__builtin_shufflevector(a, a, 0, 1),
                               __builtin_shufflevector(b, b, 0, 1), acc, false);
  acc = __builtin_amdgcn_fdot2(__builtin_shufflevector(a, a, 2, 3),
                               __builtin_shufflevector(b, b, 2, 3), acc, false);
  acc = __builtin_amdgcn_fdot2(__builtin_shufflevector(a, a, 4, 5),
                               __builtin_shufflevector(b, b, 4, 5), acc, false);
  acc = __builtin_amdgcn_fdot2(__builtin_shufflevector(a, a, 6, 7),
                               __builtin_shufflevector(b, b, 6, 7), acc, false);
  return acc;
#else
#pragma unroll
  for (int i = 0; i < 8; ++i) acc += (float)a[i] * (float)b[i];
  return acc;
#endif
}

__global__ __launch_bounds__(256, 3) void attn_kernel(
    const f16* __restrict__ Qh, const f16* __restrict__ KVh,
    const float* __restrict__ ab, float* __restrict__ out) {
  extern __shared__ f16 kv[];  // 532 slots * 56 f16 = 59584 B
  const int tid = threadIdx.x;
  const int bx = blockIdx.x * 32, by = blockIdx.y * 8;

  // ---- stage K+V halo (38x14), 6 x 16B chunks per px
  for (int idx = tid; idx < 3192; idx += 256) {
    int row = idx / 228;
    int rem = idx - row * 228;
    int pxl = rem / 6;
    int c = rem - pxl * 6;
    int gy = by + row - 3, gx = bx + pxl - 3;
    f16x8 v = {};
    if (gy >= 0 && gy < HH && gx >= 0 && gx < WW)
      v = *(const f16x8*)(KVh + ((size_t)(gy * WW + gx)) * 48 + c * 8);
    *(f16x8*)(kv + (row * 38 + pxl) * 56 + c * 8) = v;
  }
  __syncthreads();

  const int xl = tid & 31, yl = tid >> 5;
  const int p = (by + yl) * WW + bx + xl;

  f16x8 q0 = *(const f16x8*)(Qh + (size_t)p * 24);
  f16x8 q1 = *(const f16x8*)(Qh + (size_t)p * 24 + 8);
  f16x8 q2 = *(const f16x8*)(Qh + (size_t)p * 24 + 16);

  float s[49];
#pragma unroll
  for (int pp = 0; pp < 49; ++pp) {
    int dy = pp / 7, dx = pp - dy * 7;
    const f16* base = kv + ((yl + dy) * 38 + xl + dx) * 56;
    f16x8 k0 = *(const f16x8*)(base);
    f16x8 k1 = *(const f16x8*)(base + 8);
    f16x8 k2 = *(const f16x8*)(base + 16);
    float d = 0.f;
    d = dot8p(q0, k0, d);
    d = dot8p(q1, k1, d);
    d = dot8p(q2, k2, d);
    s[pp] = d * 0.20412414523193154f;  // 1/sqrt(24)
  }

  // ---- softmax over 49 positions
  float m = s[0];
#pragma unroll
  for (int pp = 1; pp < 49; ++pp) m = fmaxf(m, s[pp]);
  float den = 0.f;
#pragma unroll
  for (int pp = 0; pp < 49; ++pp) {
    float e = __expf(s[pp] - m);
    s[pp] = e;
    den += e;
  }
  const float inv = 1.f / den;

  // ---- PV accumulate in packed f16
  f16x8 y0 = {}, y1 = {}, y2 = {};
#pragma unroll
  for (int pp = 0; pp < 49; ++pp) {
    int dy = pp / 7, dx = pp - dy * 7;
    const f16* base = kv + ((yl + dy) * 38 + xl + dx) * 56 + 24;
    f16 wh = (f16)(s[pp] * inv);
    f16x8 w8 = {wh, wh, wh, wh, wh, wh, wh, wh};
    f16x8 v0 = *(const f16x8*)(base);
    f16x8 v1 = *(const f16x8*)(base + 8);
    f16x8 v2 = *(const f16x8*)(base + 16);
    y0 = v0 * w8 + y0;
    y1 = v1 * w8 + y1;
    y2 = v2 * w8 + y2;
  }

  // ---- epilogue: out[0:24] = y + a ; out[24:48] = b  (all full 128B lines)
#pragma unroll
  for (int c = 0; c < 8; ++c)
    out[(size_t)c * NN + p] = (float)y0[c] + ab[(size_t)c * NN + p];
#pragma unroll
  for (int c = 0; c < 8; ++c)
    out[(size_t)(8 + c) * NN + p] = (float)y1[c] + ab[(size_t)(8 + c) * NN + p];
#pragma unroll
  for (int c = 0; c < 8; ++c)
    out[(size_t)(16 + c) * NN + p] =
        (float)y2[c] + ab[(size_t)(16 + c) * NN + p];
#pragma unroll
  for (int c = 24; c < 48; ++c)
    out[(size_t)c * NN + p] = ab[(size_t)c * NN + p];
}

// ---------------------------------------------------------------------------
extern "C" void kernel_launch(void* const* d_in, const int* in_sizes, int n_in,
                              void* d_out, int out_size, void* d_ws,
                              size_t ws_size, hipStream_t stream) {
  const float* x = (const float*)d_in[0];
  const float* w0 = (const float*)d_in[1];
  const float* b0 = (const float*)d_in[2];
  const float* w1 = (const float*)d_in[3];
  const float* b1 = (const float*)d_in[4];
  const float* w2 = (const float*)d_in[5];
  const float* b2 = (const float*)d_in[6];
  const float* w3 = (const float*)d_in[7];
  const float* b3 = (const float*)d_in[8];
  const float* sw = (const float*)d_in[9];
  const float* sb = (const float*)d_in[10];
  const float* qw = (const float*)d_in[11];
  const float* qb = (const float*)d_in[12];
  const float* kw = (const float*)d_in[13];
  const float* kb = (const float*)d_in[14];
  const float* vw = (const float*)d_in[15];
  const float* vb = (const float*)d_in[16];
  float* out = (float*)d_out;
  float* ws = (float*)d_ws;

  // workspace layout (float units):
  float* AB = ws;                             // 48*NN (a then b, fp32 planar)
  f16* Qh = (f16*)(ws + (size_t)48 * NN);     // NN*24 f16 = 12*NN floats
  f16* KVh = (f16*)(ws + (size_t)60 * NN);    // NN*48 f16 = 24*NN floats
  f16* ACT0 = (f16*)(ws + (size_t)120 * NN);  // 2*NN*48 f16
  f16* ACT1 = (f16*)(ws + (size_t)168 * NN);  // 2*NN*48 f16
  f16* XH = (f16*)(ws + (size_t)216 * NN);    // 2*NN*4 f16 = 4*NN floats
  f16* BF = (f16*)(ws + (size_t)220 * NN);    // 75264 f16

  xh_convert<<<dim3(512), dim3(256), 0, stream>>>(x, XH);
  repack_frags<<<dim3(294), dim3(256), 0, stream>>>(w0, w1, w2, w3, BF);

  dim3 cgrd(16, 16, 2);
  conv0_gemm<<<cgrd, dim3(256), 256 * 80, stream>>>(XH, BF, b0, ACT0);
  gemm_conv<3, 48, false><<<cgrd, dim3(256), 324 * 144, stream>>>(
      ACT0, BF + 1536, b1, ACT1, nullptr, nullptr, nullptr, nullptr);
  gemm_conv<3, 48, false><<<cgrd, dim3(256), 324 * 144, stream>>>(
      ACT1, BF + 29184, b2, ACT0, nullptr, nullptr, nullptr, nullptr);
  gemm_conv<2, 24, true><<<cgrd, dim3(256), 324 * 144 + 3072, stream>>>(
      ACT0, BF + 56832, b3, nullptr, AB, x, sw, sb);

  qkv_kernel<<<dim3(256), dim3(256), 0, stream>>>(AB, AB + 24 * NN, qw, qb, kw,
                                                  kb, vw, vb, Qh, KVh);

  attn_kernel<<<dim3(8, 32), dim3(256), 532 * 112, stream>>>(Qh, KVh, AB, out);
}

// Round 8
// 159.272 us; speedup vs baseline: 8.6518x; 1.1612x over previous
//
#include <hip/hip_runtime.h>
#include <math.h>

#define HH 256
#define WW 256
#define NN (HH * WW)

typedef _Float16 f16;
typedef _Float16 f16x8 __attribute__((ext_vector_type(8)));
typedef _Float16 f16x4 __attribute__((ext_vector_type(4)));
typedef float f32x4 __attribute__((ext_vector_type(4)));

// ---------------------------------------------------------------------------
// x (2 streams, NCHW fp32, 3ch) -> xh NHWC fp16 4ch (c3 = 0 pad)
// ---------------------------------------------------------------------------
__global__ __launch_bounds__(256) void xh_convert(const float* __restrict__ x,
                                                  f16* __restrict__ xh) {
  int p = blockIdx.x * 256 + threadIdx.x;  // 0..2*NN-1
  int z = p >= NN;
  int q = p - z * NN;
  const float* xz = x + (size_t)z * 3 * NN;
  f16x4 v;
  v[0] = (f16)xz[q];
  v[1] = (f16)xz[NN + q];
  v[2] = (f16)xz[2 * NN + q];
  v[3] = (f16)0.f;
  *(f16x4*)(xh + (size_t)p * 4) = v;
}

// ---------------------------------------------------------------------------
// Repack weights into MFMA B-fragments (f16): B[k=quad*8+j][n=lane&15].
// conv L0 @0 (1536), L1 @1536, L2 @29184, L3 @56832 (each [nt][tap][kc][lane][j])
// qkv:  QF @75264, KF @76288, VF @77312  ([nt:2][lane:64][j:8], k=ci pad 32)
// total 78336 f16.
// ---------------------------------------------------------------------------
__global__ __launch_bounds__(256) void repack_frags(
    const float* __restrict__ w0, const float* __restrict__ w1,
    const float* __restrict__ w2, const float* __restrict__ w3,
    const float* __restrict__ qw, const float* __restrict__ kw,
    const float* __restrict__ vw, f16* __restrict__ bf) {
  const int O1 = 1536, O2 = O1 + 27648, O3 = O2 + 27648, OQ = O3 + 18432;
  int e = blockIdx.x * 256 + threadIdx.x;
  if (e >= OQ + 3072) return;
  float val = 0.f;
  if (e >= OQ) {  // qkv B-frags
    int idx = e - OQ;
    int mat = idx >> 10;           // 0=Q 1=K 2=V
    int r = idx & 1023;
    int nt = r >> 9;
    int lane = (r >> 3) & 63;
    int j = r & 7;
    int n = lane & 15, quad = lane >> 4;
    int ci = quad * 8 + j, co = nt * 16 + n;
    const float* w = (mat == 0) ? qw : (mat == 1) ? kw : vw;
    if (ci < 24 && co < 24) val = w[co * 24 + ci];
  } else {
    const float* w;
    int COUT, idx, mode;
    if (e < O1)      { w = w0; COUT = 48; idx = e;      mode = 0; }
    else if (e < O2) { w = w1; COUT = 48; idx = e - O1; mode = 1; }
    else if (e < O3) { w = w2; COUT = 48; idx = e - O2; mode = 1; }
    else             { w = w3; COUT = 24; idx = e - O3; mode = 1; }
    int j = idx & 7;
    int lane = (idx >> 3) & 63;
    int rest = idx >> 9;
    int n = lane & 15, quad = lane >> 4;
    if (mode == 0) {
      int nt = rest;
      int k = quad * 8 + j;
      int cout = nt * 16 + n;
      if (k < 27) {
        int tap = k / 3, ci = k - tap * 3;
        val = w[(cout * 3 + ci) * 9 + tap];  // OIHW, tap = dy*3+dx
      }
    } else {
      int kc = rest & 1;
      int tap = (rest >> 1) % 9;
      int nt = (rest >> 1) / 9;
      int ci = kc * 32 + quad * 8 + j;
      int cout = nt * 16 + n;
      if (ci < 48 && cout < COUT) val = w[(cout * 48 + ci) * 9 + tap];
    }
  }
  bf[e] = (f16)val;
}

// ---------------------------------------------------------------------------
// Layer 0: 3->48, K=27 padded to 32. Direct im2col A-panel in LDS.
// ---------------------------------------------------------------------------
__global__ __launch_bounds__(256, 2) void conv0_gemm(
    const f16* __restrict__ xh, const f16* __restrict__ bf0,
    const float* __restrict__ bias, f16* __restrict__ outh) {
  extern __shared__ char smem[];  // 256*80 B
  const int tid = threadIdx.x;
  const int lane = tid & 63, wave = tid >> 6;
  const int n = lane & 15, quad = lane >> 4;
  const int bx = blockIdx.x * 16, by = blockIdx.y * 16, z = blockIdx.z;
  const f16* xz = xh + (size_t)z * NN * 4;

  {
    int p = tid, y = p >> 4, xcol = p & 15;
    int gy = by + y, gx = bx + xcol;
    f16* row = (f16*)(smem + p * 80);
#pragma unroll
    for (int tap = 0; tap < 9; ++tap) {
      int dy = tap / 3, dx = tap - (tap / 3) * 3;
      int sy = gy + dy - 1, sx = gx + dx - 1;
      f16 c0 = (f16)0.f, c1 = c0, c2 = c0;
      if (sy >= 0 && sy < HH && sx >= 0 && sx < WW) {
        const f16* s = xz + ((size_t)sy * WW + sx) * 4;
        c0 = s[0]; c1 = s[1]; c2 = s[2];
      }
      row[tap * 3 + 0] = c0;
      row[tap * 3 + 1] = c1;
      row[tap * 3 + 2] = c2;
    }
#pragma unroll
    for (int k = 27; k < 32; ++k) row[k] = (f16)0.f;
  }
  __syncthreads();

  f32x4 acc[4][3];
#pragma unroll
  for (int nt = 0; nt < 3; ++nt) {
    float bv = bias[nt * 16 + n];
#pragma unroll
    for (int i = 0; i < 4; ++i) acc[i][nt] = (f32x4){bv, bv, bv, bv};
  }
  f16x8 B[3];
#pragma unroll
  for (int nt = 0; nt < 3; ++nt)
    B[nt] = *(const f16x8*)(bf0 + (nt * 64 + lane) * 8);
#pragma unroll
  for (int i = 0; i < 4; ++i) {
    int r = wave * 4 + i;
    f16x8 a = *(const f16x8*)(smem + (r * 16 + n) * 80 + quad * 16);
#pragma unroll
    for (int nt = 0; nt < 3; ++nt)
      acc[i][nt] =
          __builtin_amdgcn_mfma_f32_16x16x32_f16(a, B[nt], acc[i][nt], 0, 0, 0);
  }

  f16* oz = outh + (size_t)z * NN * 48;
#pragma unroll
  for (int i = 0; i < 4; ++i) {
    int y = by + wave * 4 + i;
#pragma unroll
    for (int nt = 0; nt < 3; ++nt)
#pragma unroll
      for (int reg = 0; reg < 4; ++reg)
        oz[((size_t)y * WW + bx + quad * 4 + reg) * 48 + nt * 16 + n] =
            (f16)fmaxf(acc[i][nt][reg], 0.f);
  }
}

// ---------------------------------------------------------------------------
// Layers 1-3: 48->COUT implicit GEMM. FUSE (layer 3): epilogue adds 1x1
// skip conv and writes ABh = NHWC f16, 32ch/px (24 valid + 8 zero pad) —
// the MFMA-A-friendly layout consumed by qkv_mfma and the attn epilogue.
// ---------------------------------------------------------------------------
template <int NT, int COUT, bool FUSE>
__global__ __launch_bounds__(256, 2) void gemm_conv(
    const f16* __restrict__ in, const f16* __restrict__ bfr,
    const float* __restrict__ bias, f16* __restrict__ outh,
    const float* __restrict__ xsrc, const float* __restrict__ skw,
    const float* __restrict__ skb) {
  extern __shared__ char smem[];           // 324*144 (+3KB xt if FUSE)
  float* xt = (float*)(smem + 324 * 144);  // [c:3][y:16][x:16]
  const int tid = threadIdx.x;
  const int lane = tid & 63, wave = tid >> 6;
  const int n = lane & 15, quad = lane >> 4;
  const int bx = blockIdx.x * 16, by = blockIdx.y * 16, z = blockIdx.z;
  const f16* inz = in + (size_t)z * NN * 48;

  for (int p = tid; p < 324; p += 256) {
    int yy = p / 18, xx = p - yy * 18;
    int gy = by + yy - 1, gx = bx + xx - 1;
    float4* dst = (float4*)(smem + p * 144);
    if (gy >= 0 && gy < HH && gx >= 0 && gx < WW) {
      const float4* s = (const float4*)(inz + ((size_t)gy * WW + gx) * 48);
      float4 a0 = s[0], a1 = s[1], a2 = s[2], a3 = s[3], a4 = s[4], a5 = s[5];
      dst[0] = a0; dst[1] = a1; dst[2] = a2;
      dst[3] = a3; dst[4] = a4; dst[5] = a5;
      dst[6] = make_float4(0, 0, 0, 0);
      dst[7] = make_float4(0, 0, 0, 0);
    } else {
      float4 zz = make_float4(0, 0, 0, 0);
#pragma unroll
      for (int c = 0; c < 8; ++c) dst[c] = zz;
    }
  }
  if (FUSE) {
    for (int i = tid; i < 768; i += 256) {
      int c = i >> 8, p = i & 255;
      xt[i] = xsrc[(size_t)z * 3 * NN + c * NN + (by + (p >> 4)) * WW + bx +
                   (p & 15)];
    }
  }
  __syncthreads();

  f32x4 acc[4][NT];
#pragma unroll
  for (int nt = 0; nt < NT; ++nt) {
    int cc = nt * 16 + n;
    float bv = (cc < COUT) ? bias[cc] : 0.f;
#pragma unroll
    for (int i = 0; i < 4; ++i) acc[i][nt] = (f32x4){bv, bv, bv, bv};
  }

  const int r0 = wave * 4;
#pragma unroll
  for (int tap = 0; tap < 9; ++tap) {
    const int dy = tap / 3, dx = tap - dy * 3;
    f16x8 B[2][NT];
#pragma unroll
    for (int kc = 0; kc < 2; ++kc)
#pragma unroll
      for (int nt = 0; nt < NT; ++nt)
        B[kc][nt] =
            *(const f16x8*)(bfr + (((nt * 9 + tap) * 2 + kc) * 64 + lane) * 8);
#pragma unroll
    for (int i = 0; i < 4; ++i) {
      const int p = (r0 + i + dy) * 18 + (n + dx);
      const char* ap = smem + p * 144;
      f16x8 a0 = *(const f16x8*)(ap + quad * 16);
      f16x8 a1 = *(const f16x8*)(ap + 64 + quad * 16);
#pragma unroll
      for (int nt = 0; nt < NT; ++nt)
        acc[i][nt] = __builtin_amdgcn_mfma_f32_16x16x32_f16(a0, B[0][nt],
                                                            acc[i][nt], 0, 0, 0);
#pragma unroll
      for (int nt = 0; nt < NT; ++nt)
        acc[i][nt] = __builtin_amdgcn_mfma_f32_16x16x32_f16(a1, B[1][nt],
                                                            acc[i][nt], 0, 0, 0);
    }
  }

  if (!FUSE) {
    f16* oz = outh + (size_t)z * NN * 48;
#pragma unroll
    for (int i = 0; i < 4; ++i) {
      int y = by + r0 + i;
#pragma unroll
      for (int nt = 0; nt < NT; ++nt)
#pragma unroll
        for (int reg = 0; reg < 4; ++reg)
          oz[((size_t)y * WW + bx + quad * 4 + reg) * 48 + nt * 16 + n] =
              (f16)fmaxf(acc[i][nt][reg], 0.f);
    }
  } else {
    f16* oz = outh + (size_t)z * NN * 32;  // ABh stream base
#pragma unroll
    for (int i = 0; i < 4; ++i) {
      int y = by + r0 + i;
#pragma unroll
      for (int nt = 0; nt < NT; ++nt) {
        int cc = nt * 16 + n;
        float s0 = 0.f, s1 = 0.f, s2 = 0.f, sb0 = 0.f;
        if (cc < 24) {
          s0 = skw[cc * 3 + 0];
          s1 = skw[cc * 3 + 1];
          s2 = skw[cc * 3 + 2];
          sb0 = skb[cc];
        }
#pragma unroll
        for (int reg = 0; reg < 4; ++reg) {
          float v = 0.f;
          if (cc < 24) {
            int pl = (r0 + i) * 16 + quad * 4 + reg;
            float sk = sb0 + s0 * xt[pl] + s1 * xt[256 + pl] + s2 * xt[512 + pl];
            v = fmaxf(acc[i][nt][reg], 0.f) + sk;
          }
          oz[((size_t)(y * WW + bx + quad * 4 + reg)) * 32 + cc] = (f16)v;
        }
      }
    }
  }
}

// ---------------------------------------------------------------------------
// QKV via MFMA. grid (256, 2): z=0 computes K,V from ABh stream a; z=1
// computes Q from stream b. Each wave: 4 independent 16-px M-tiles; A-frag is
// ONE perfectly-coalesced global b128 per tile (ABh layout IS A-layout);
// weights are pre-repacked B-frags (no scalar-weight lgkmcnt drains — the R2
// failure mode that made the old VALU qkv latency-bound).
// ---------------------------------------------------------------------------
__global__ __launch_bounds__(256) void qkv_mfma(
    const f16* __restrict__ ABh, const f16* __restrict__ bf,
    const float* __restrict__ qb, const float* __restrict__ kb,
    const float* __restrict__ vb, f16* __restrict__ Qh,
    f16* __restrict__ KVh) {
  const int OQ = 75264;
  const int tid = threadIdx.x;
  const int lane = tid & 63, wave = tid >> 6;
  const int n = lane & 15, quad = lane >> 4;
  const int z = blockIdx.y;
  const f16* src = ABh + (size_t)z * NN * 32;

  if (z == 1) {  // ---- Q from b
    f16x8 QF[2];
#pragma unroll
    for (int nt = 0; nt < 2; ++nt)
      QF[nt] = *(const f16x8*)(bf + OQ + (nt * 64 + lane) * 8);
    float qbias[2];
#pragma unroll
    for (int nt = 0; nt < 2; ++nt) {
      int cc = nt * 16 + n;
      qbias[nt] = (cc < 24) ? qb[cc] : 0.f;
    }
#pragma unroll
    for (int t = 0; t < 4; ++t) {
      int T = blockIdx.x * 16 + wave * 4 + t;
      size_t p0 = (size_t)T * 16;
      f16x8 a8 = *(const f16x8*)(src + p0 * 32 + n * 32 + quad * 8);
#pragma unroll
      for (int nt = 0; nt < 2; ++nt) {
        f32x4 acc = {qbias[nt], qbias[nt], qbias[nt], qbias[nt]};
        acc = __builtin_amdgcn_mfma_f32_16x16x32_f16(a8, QF[nt], acc, 0, 0, 0);
        int cc = nt * 16 + n;
        if (cc < 24) {
#pragma unroll
          for (int reg = 0; reg < 4; ++reg)
            Qh[(p0 + quad * 4 + reg) * 24 + cc] = (f16)acc[reg];
        }
      }
    }
  } else {  // ---- K,V from a
    f16x8 KF[2], VF[2];
#pragma unroll
    for (int nt = 0; nt < 2; ++nt) {
      KF[nt] = *(const f16x8*)(bf + OQ + 1024 + (nt * 64 + lane) * 8);
      VF[nt] = *(const f16x8*)(bf + OQ + 2048 + (nt * 64 + lane) * 8);
    }
    float kbias[2], vbias[2];
#pragma unroll
    for (int nt = 0; nt < 2; ++nt) {
      int cc = nt * 16 + n;
      kbias[nt] = (cc < 24) ? kb[cc] : 0.f;
      vbias[nt] = (cc < 24) ? vb[cc] : 0.f;
    }
#pragma unroll
    for (int t = 0; t < 4; ++t) {
      int T = blockIdx.x * 16 + wave * 4 + t;
      size_t p0 = (size_t)T * 16;
      f16x8 a8 = *(const f16x8*)(src + p0 * 32 + n * 32 + quad * 8);
#pragma unroll
      for (int nt = 0; nt < 2; ++nt) {
        f32x4 ak = {kbias[nt], kbias[nt], kbias[nt], kbias[nt]};
        f32x4 av = {vbias[nt], vbias[nt], vbias[nt], vbias[nt]};
        ak = __builtin_amdgcn_mfma_f32_16x16x32_f16(a8, KF[nt], ak, 0, 0, 0);
        av = __builtin_amdgcn_mfma_f32_16x16x32_f16(a8, VF[nt], av, 0, 0, 0);
        int cc = nt * 16 + n;
        if (cc < 24) {
#pragma unroll
          for (int reg = 0; reg < 4; ++reg) {
            KVh[(p0 + quad * 4 + reg) * 48 + cc] = (f16)ak[reg];
            KVh[(p0 + quad * 4 + reg) * 48 + 24 + cc] = (f16)av[reg];
          }
        }
      }
    }
  }
}

// ---------------------------------------------------------------------------
// Attention. 32x8 px tile / 256 threads, grid (8,32). Single K+V LDS stage
// (38x14 halo, 112B/px). Q loads hoisted above staging (overlap the barrier
// at 1 wave/SIMD). Epilogue reads ABh f16 (a add + b passthrough).
// ---------------------------------------------------------------------------
__device__ inline float dot8p(f16x8 a, f16x8 b, float acc) {
#if __has_builtin(__builtin_amdgcn_fdot2)
  acc = __builtin_amdgcn_fdot2(__builtin_shufflevector(a, a, 0, 1),
                               __builtin_shufflevector(b, b, 0, 1), acc, false);
  acc = __builtin_amdgcn_fdot2(__builtin_shufflevector(a, a, 2, 3),
                               __builtin_shufflevector(b, b, 2, 3), acc, false);
  acc = __builtin_amdgcn_fdot2(__builtin_shufflevector(a, a, 4, 5),
                               __builtin_shufflevector(b, b, 4, 5), acc, false);
  acc = __builtin_amdgcn_fdot2(__builtin_shufflevector(a, a, 6, 7),
                               __builtin_shufflevector(b, b, 6, 7), acc, false);
  return acc;
#else
#pragma unroll
  for (int i = 0; i < 8; ++i) acc += (float)a[i] * (float)b[i];
  return acc;
#endif
}

__global__ __launch_bounds__(256, 3) void attn_kernel(
    const f16* __restrict__ Qh, const f16* __restrict__ KVh,
    const f16* __restrict__ ABh, float* __restrict__ out) {
  extern __shared__ f16 kv[];  // 532 slots * 56 f16 = 59584 B
  const int tid = threadIdx.x;
  const int bx = blockIdx.x * 32, by = blockIdx.y * 8;
  const int xl = tid & 31, yl = tid >> 5;
  const int p = (by + yl) * WW + bx + xl;

  // Q loads issued before staging so they overlap the stage + barrier.
  f16x8 q0 = *(const f16x8*)(Qh + (size_t)p * 24);
  f16x8 q1 = *(const f16x8*)(Qh + (size_t)p * 24 + 8);
  f16x8 q2 = *(const f16x8*)(Qh + (size_t)p * 24 + 16);

  for (int idx = tid; idx < 3192; idx += 256) {
    int row = idx / 228;
    int rem = idx - row * 228;
    int pxl = rem / 6;
    int c = rem - pxl * 6;
    int gy = by + row - 3, gx = bx + pxl - 3;
    f16x8 v = {};
    if (gy >= 0 && gy < HH && gx >= 0 && gx < WW)
      v = *(const f16x8*)(KVh + ((size_t)(gy * WW + gx)) * 48 + c * 8);
    *(f16x8*)(kv + (row * 38 + pxl) * 56 + c * 8) = v;
  }
  __syncthreads();

  float s[49];
#pragma unroll
  for (int pp = 0; pp < 49; ++pp) {
    int dy = pp / 7, dx = pp - dy * 7;
    const f16* base = kv + ((yl + dy) * 38 + xl + dx) * 56;
    f16x8 k0 = *(const f16x8*)(base);
    f16x8 k1 = *(const f16x8*)(base + 8);
    f16x8 k2 = *(const f16x8*)(base + 16);
    float d = 0.f;
    d = dot8p(q0, k0, d);
    d = dot8p(q1, k1, d);
    d = dot8p(q2, k2, d);
    s[pp] = d * 0.20412414523193154f;  // 1/sqrt(24)
  }

  float m = s[0];
#pragma unroll
  for (int pp = 1; pp < 49; ++pp) m = fmaxf(m, s[pp]);
  float den = 0.f;
#pragma unroll
  for (int pp = 0; pp < 49; ++pp) {
    float e = __expf(s[pp] - m);
    s[pp] = e;
    den += e;
  }
  const float inv = 1.f / den;

  f16x8 y0 = {}, y1 = {}, y2 = {};
#pragma unroll
  for (int pp = 0; pp < 49; ++pp) {
    int dy = pp / 7, dx = pp - dy * 7;
    const f16* base = kv + ((yl + dy) * 38 + xl + dx) * 56 + 24;
    f16 wh = (f16)(s[pp] * inv);
    f16x8 w8 = {wh, wh, wh, wh, wh, wh, wh, wh};
    f16x8 v0 = *(const f16x8*)(base);
    f16x8 v1 = *(const f16x8*)(base + 8);
    f16x8 v2 = *(const f16x8*)(base + 16);
    y0 = v0 * w8 + y0;
    y1 = v1 * w8 + y1;
    y2 = v2 * w8 + y2;
  }

  const f16* ah = ABh + (size_t)p * 32;
  const f16* bh = ABh + (size_t)NN * 32 + (size_t)p * 32;
  f16x8 a0 = *(const f16x8*)(ah);
  f16x8 a1 = *(const f16x8*)(ah + 8);
  f16x8 a2 = *(const f16x8*)(ah + 16);
  f16x8 b0 = *(const f16x8*)(bh);
  f16x8 b1 = *(const f16x8*)(bh + 8);
  f16x8 b2 = *(const f16x8*)(bh + 16);
#pragma unroll
  for (int c = 0; c < 8; ++c) {
    out[(size_t)c * NN + p] = (float)y0[c] + (float)a0[c];
    out[(size_t)(8 + c) * NN + p] = (float)y1[c] + (float)a1[c];
    out[(size_t)(16 + c) * NN + p] = (float)y2[c] + (float)a2[c];
    out[(size_t)(24 + c) * NN + p] = (float)b0[c];
    out[(size_t)(32 + c) * NN + p] = (float)b1[c];
    out[(size_t)(40 + c) * NN + p] = (float)b2[c];
  }
}

// ---------------------------------------------------------------------------
extern "C" void kernel_launch(void* const* d_in, const int* in_sizes, int n_in,
                              void* d_out, int out_size, void* d_ws,
                              size_t ws_size, hipStream_t stream) {
  const float* x = (const float*)d_in[0];
  const float* w0 = (const float*)d_in[1];
  const float* b0 = (const float*)d_in[2];
  const float* w1 = (const float*)d_in[3];
  const float* b1 = (const float*)d_in[4];
  const float* w2 = (const float*)d_in[5];
  const float* b2 = (const float*)d_in[6];
  const float* w3 = (const float*)d_in[7];
  const float* b3 = (const float*)d_in[8];
  const float* sw = (const float*)d_in[9];
  const float* sb = (const float*)d_in[10];
  const float* qw = (const float*)d_in[11];
  const float* qb = (const float*)d_in[12];
  const float* kw = (const float*)d_in[13];
  const float* kb = (const float*)d_in[14];
  const float* vw = (const float*)d_in[15];
  const float* vb = (const float*)d_in[16];
  float* out = (float*)d_out;
  float* ws = (float*)d_ws;

  // workspace layout (float units), all regions disjoint:
  f16* Qh = (f16*)(ws);                       // NN*24 f16 = 12*NN floats
  f16* KVh = (f16*)(ws + (size_t)12 * NN);    // NN*48 f16 = 24*NN floats
  f16* ABh = (f16*)(ws + (size_t)36 * NN);    // 2*NN*32 f16 = 32*NN floats
  f16* ACT0 = (f16*)(ws + (size_t)68 * NN);   // 2*NN*48 f16 = 48*NN floats
  f16* ACT1 = (f16*)(ws + (size_t)116 * NN);  // 48*NN floats
  f16* XH = (f16*)(ws + (size_t)164 * NN);    // 4*NN floats
  f16* BF = (f16*)(ws + (size_t)168 * NN);    // 78336 f16

  xh_convert<<<dim3(512), dim3(256), 0, stream>>>(x, XH);
  repack_frags<<<dim3(306), dim3(256), 0, stream>>>(w0, w1, w2, w3, qw, kw, vw,
                                                    BF);

  dim3 cgrd(16, 16, 2);
  conv0_gemm<<<cgrd, dim3(256), 256 * 80, stream>>>(XH, BF, b0, ACT0);
  gemm_conv<3, 48, false><<<cgrd, dim3(256), 324 * 144, stream>>>(
      ACT0, BF + 1536, b1, ACT1, nullptr, nullptr, nullptr);
  gemm_conv<3, 48, false><<<cgrd, dim3(256), 324 * 144, stream>>>(
      ACT1, BF + 29184, b2, ACT0, nullptr, nullptr, nullptr);
  gemm_conv<2, 24, true><<<cgrd, dim3(256), 324 * 144 + 3072, stream>>>(
      ACT0, BF + 56832, b3, ABh, x, sw, sb);

  qkv_mfma<<<dim3(256, 2), dim3(256), 0, stream>>>(ABh, BF, qb, kb, vb, Qh,
                                                   KVh);

  attn_kernel<<<dim3(8, 32), dim3(256), 532 * 112, stream>>>(Qh, KVh, ABh, out);
}

// Round 9
// 155.371 us; speedup vs baseline: 8.8691x; 1.0251x over previous
//
#include <hip/hip_runtime.h>
#include <math.h>

#define HH 256
#define WW 256
#define NN (HH * WW)

typedef _Float16 f16;
typedef _Float16 f16x8 __attribute__((ext_vector_type(8)));
typedef _Float16 f16x4 __attribute__((ext_vector_type(4)));
typedef float f32x4 __attribute__((ext_vector_type(4)));

#define OQ 75264  // qkv B-frag base inside BF (f16 units)

// ---------------------------------------------------------------------------
// Prep (merged): blocks 0..511 convert x -> XH (NHWC f16 4ch);
// blocks 512..817 repack weights into MFMA B-fragments.
// BF layout: conv L0 @0, L1 @1536, L2 @29184, L3 @56832;
// qkv QF @OQ, KF @OQ+1024, VF @OQ+2048; total 78336 f16.
// ---------------------------------------------------------------------------
__global__ __launch_bounds__(256) void prep_kernel(
    const float* __restrict__ x, const float* __restrict__ w0,
    const float* __restrict__ w1, const float* __restrict__ w2,
    const float* __restrict__ w3, const float* __restrict__ qw,
    const float* __restrict__ kw, const float* __restrict__ vw,
    f16* __restrict__ xh, f16* __restrict__ bf) {
  if (blockIdx.x < 512) {
    int p = blockIdx.x * 256 + threadIdx.x;  // 0..2*NN-1
    int z = p >= NN;
    int q = p - z * NN;
    const float* xz = x + (size_t)z * 3 * NN;
    f16x4 v;
    v[0] = (f16)xz[q];
    v[1] = (f16)xz[NN + q];
    v[2] = (f16)xz[2 * NN + q];
    v[3] = (f16)0.f;
    *(f16x4*)(xh + (size_t)p * 4) = v;
    return;
  }
  const int O1 = 1536, O2 = O1 + 27648, O3 = O2 + 27648;
  int e = (blockIdx.x - 512) * 256 + threadIdx.x;
  if (e >= OQ + 3072) return;
  float val = 0.f;
  if (e >= OQ) {  // qkv B-frags
    int idx = e - OQ;
    int mat = idx >> 10;  // 0=Q 1=K 2=V
    int r = idx & 1023;
    int nt = r >> 9;
    int lane = (r >> 3) & 63;
    int j = r & 7;
    int n = lane & 15, quad = lane >> 4;
    int ci = quad * 8 + j, co = nt * 16 + n;
    const float* w = (mat == 0) ? qw : (mat == 1) ? kw : vw;
    if (ci < 24 && co < 24) val = w[co * 24 + ci];
  } else {
    const float* w;
    int COUT, idx, mode;
    if (e < O1)      { w = w0; COUT = 48; idx = e;      mode = 0; }
    else if (e < O2) { w = w1; COUT = 48; idx = e - O1; mode = 1; }
    else if (e < O3) { w = w2; COUT = 48; idx = e - O2; mode = 1; }
    else             { w = w3; COUT = 24; idx = e - O3; mode = 1; }
    int j = idx & 7;
    int lane = (idx >> 3) & 63;
    int rest = idx >> 9;
    int n = lane & 15, quad = lane >> 4;
    if (mode == 0) {
      int nt = rest;
      int k = quad * 8 + j;
      int cout = nt * 16 + n;
      if (k < 27) {
        int tap = k / 3, ci = k - tap * 3;
        val = w[(cout * 3 + ci) * 9 + tap];  // OIHW, tap = dy*3+dx
      }
    } else {
      int kc = rest & 1;
      int tap = (rest >> 1) % 9;
      int nt = (rest >> 1) / 9;
      int ci = kc * 32 + quad * 8 + j;
      int cout = nt * 16 + n;
      if (ci < 48 && cout < COUT) val = w[(cout * 48 + ci) * 9 + tap];
    }
  }
  bf[e] = (f16)val;
}

// ---------------------------------------------------------------------------
// Layer 0: 3->48, K=27 padded to 32. Direct im2col A-panel in LDS.
// ---------------------------------------------------------------------------
__global__ __launch_bounds__(256, 2) void conv0_gemm(
    const f16* __restrict__ xh, const f16* __restrict__ bf0,
    const float* __restrict__ bias, f16* __restrict__ outh) {
  extern __shared__ char smem[];  // 256*80 B
  const int tid = threadIdx.x;
  const int lane = tid & 63, wave = tid >> 6;
  const int n = lane & 15, quad = lane >> 4;
  const int bx = blockIdx.x * 16, by = blockIdx.y * 16, z = blockIdx.z;
  const f16* xz = xh + (size_t)z * NN * 4;

  {
    int p = tid, y = p >> 4, xcol = p & 15;
    int gy = by + y, gx = bx + xcol;
    f16* row = (f16*)(smem + p * 80);
#pragma unroll
    for (int tap = 0; tap < 9; ++tap) {
      int dy = tap / 3, dx = tap - (tap / 3) * 3;
      int sy = gy + dy - 1, sx = gx + dx - 1;
      f16 c0 = (f16)0.f, c1 = c0, c2 = c0;
      if (sy >= 0 && sy < HH && sx >= 0 && sx < WW) {
        const f16* s = xz + ((size_t)sy * WW + sx) * 4;
        c0 = s[0]; c1 = s[1]; c2 = s[2];
      }
      row[tap * 3 + 0] = c0;
      row[tap * 3 + 1] = c1;
      row[tap * 3 + 2] = c2;
    }
#pragma unroll
    for (int k = 27; k < 32; ++k) row[k] = (f16)0.f;
  }
  __syncthreads();

  f32x4 acc[4][3];
#pragma unroll
  for (int nt = 0; nt < 3; ++nt) {
    float bv = bias[nt * 16 + n];
#pragma unroll
    for (int i = 0; i < 4; ++i) acc[i][nt] = (f32x4){bv, bv, bv, bv};
  }
  f16x8 B[3];
#pragma unroll
  for (int nt = 0; nt < 3; ++nt)
    B[nt] = *(const f16x8*)(bf0 + (nt * 64 + lane) * 8);
#pragma unroll
  for (int i = 0; i < 4; ++i) {
    int r = wave * 4 + i;
    f16x8 a = *(const f16x8*)(smem + (r * 16 + n) * 80 + quad * 16);
#pragma unroll
    for (int nt = 0; nt < 3; ++nt)
      acc[i][nt] =
          __builtin_amdgcn_mfma_f32_16x16x32_f16(a, B[nt], acc[i][nt], 0, 0, 0);
  }

  f16* oz = outh + (size_t)z * NN * 48;
#pragma unroll
  for (int i = 0; i < 4; ++i) {
    int y = by + wave * 4 + i;
#pragma unroll
    for (int nt = 0; nt < 3; ++nt)
#pragma unroll
      for (int reg = 0; reg < 4; ++reg)
        oz[((size_t)y * WW + bx + quad * 4 + reg) * 48 + nt * 16 + n] =
            (f16)fmaxf(acc[i][nt][reg], 0.f);
  }
}

// ---------------------------------------------------------------------------
// Layers 1-3: 48->COUT implicit GEMM (unchanged). FUSE writes ABh NHWC f16
// 32ch/px (24 valid + 8 zero pad).
// ---------------------------------------------------------------------------
template <int NT, int COUT, bool FUSE>
__global__ __launch_bounds__(256, 2) void gemm_conv(
    const f16* __restrict__ in, const f16* __restrict__ bfr,
    const float* __restrict__ bias, f16* __restrict__ outh,
    const float* __restrict__ xsrc, const float* __restrict__ skw,
    const float* __restrict__ skb) {
  extern __shared__ char smem[];           // 324*144 (+3KB xt if FUSE)
  float* xt = (float*)(smem + 324 * 144);  // [c:3][y:16][x:16]
  const int tid = threadIdx.x;
  const int lane = tid & 63, wave = tid >> 6;
  const int n = lane & 15, quad = lane >> 4;
  const int bx = blockIdx.x * 16, by = blockIdx.y * 16, z = blockIdx.z;
  const f16* inz = in + (size_t)z * NN * 48;

  for (int p = tid; p < 324; p += 256) {
    int yy = p / 18, xx = p - yy * 18;
    int gy = by + yy - 1, gx = bx + xx - 1;
    float4* dst = (float4*)(smem + p * 144);
    if (gy >= 0 && gy < HH && gx >= 0 && gx < WW) {
      const float4* s = (const float4*)(inz + ((size_t)gy * WW + gx) * 48);
      float4 a0 = s[0], a1 = s[1], a2 = s[2], a3 = s[3], a4 = s[4], a5 = s[5];
      dst[0] = a0; dst[1] = a1; dst[2] = a2;
      dst[3] = a3; dst[4] = a4; dst[5] = a5;
      dst[6] = make_float4(0, 0, 0, 0);
      dst[7] = make_float4(0, 0, 0, 0);
    } else {
      float4 zz = make_float4(0, 0, 0, 0);
#pragma unroll
      for (int c = 0; c < 8; ++c) dst[c] = zz;
    }
  }
  if (FUSE) {
    for (int i = tid; i < 768; i += 256) {
      int c = i >> 8, p = i & 255;
      xt[i] = xsrc[(size_t)z * 3 * NN + c * NN + (by + (p >> 4)) * WW + bx +
                   (p & 15)];
    }
  }
  __syncthreads();

  f32x4 acc[4][NT];
#pragma unroll
  for (int nt = 0; nt < NT; ++nt) {
    int cc = nt * 16 + n;
    float bv = (cc < COUT) ? bias[cc] : 0.f;
#pragma unroll
    for (int i = 0; i < 4; ++i) acc[i][nt] = (f32x4){bv, bv, bv, bv};
  }

  const int r0 = wave * 4;
#pragma unroll
  for (int tap = 0; tap < 9; ++tap) {
    const int dy = tap / 3, dx = tap - dy * 3;
    f16x8 B[2][NT];
#pragma unroll
    for (int kc = 0; kc < 2; ++kc)
#pragma unroll
      for (int nt = 0; nt < NT; ++nt)
        B[kc][nt] =
            *(const f16x8*)(bfr + (((nt * 9 + tap) * 2 + kc) * 64 + lane) * 8);
#pragma unroll
    for (int i = 0; i < 4; ++i) {
      const int p = (r0 + i + dy) * 18 + (n + dx);
      const char* ap = smem + p * 144;
      f16x8 a0 = *(const f16x8*)(ap + quad * 16);
      f16x8 a1 = *(const f16x8*)(ap + 64 + quad * 16);
#pragma unroll
      for (int nt = 0; nt < NT; ++nt)
        acc[i][nt] = __builtin_amdgcn_mfma_f32_16x16x32_f16(a0, B[0][nt],
                                                            acc[i][nt], 0, 0, 0);
#pragma unroll
      for (int nt = 0; nt < NT; ++nt)
        acc[i][nt] = __builtin_amdgcn_mfma_f32_16x16x32_f16(a1, B[1][nt],
                                                            acc[i][nt], 0, 0, 0);
    }
  }

  if (!FUSE) {
    f16* oz = outh + (size_t)z * NN * 48;
#pragma unroll
    for (int i = 0; i < 4; ++i) {
      int y = by + r0 + i;
#pragma unroll
      for (int nt = 0; nt < NT; ++nt)
#pragma unroll
        for (int reg = 0; reg < 4; ++reg)
          oz[((size_t)y * WW + bx + quad * 4 + reg) * 48 + nt * 16 + n] =
              (f16)fmaxf(acc[i][nt][reg], 0.f);
    }
  } else {
    f16* oz = outh + (size_t)z * NN * 32;  // ABh stream base
#pragma unroll
    for (int i = 0; i < 4; ++i) {
      int y = by + r0 + i;
#pragma unroll
      for (int nt = 0; nt < NT; ++nt) {
        int cc = nt * 16 + n;
        float s0 = 0.f, s1 = 0.f, s2 = 0.f, sb0 = 0.f;
        if (cc < 24) {
          s0 = skw[cc * 3 + 0];
          s1 = skw[cc * 3 + 1];
          s2 = skw[cc * 3 + 2];
          sb0 = skb[cc];
        }
#pragma unroll
        for (int reg = 0; reg < 4; ++reg) {
          float v = 0.f;
          if (cc < 24) {
            int pl = (r0 + i) * 16 + quad * 4 + reg;
            float sk = sb0 + s0 * xt[pl] + s1 * xt[256 + pl] + s2 * xt[512 + pl];
            v = fmaxf(acc[i][nt][reg], 0.f) + sk;
          }
          oz[((size_t)(y * WW + bx + quad * 4 + reg)) * 32 + cc] = (f16)v;
        }
      }
    }
  }
}

// ---------------------------------------------------------------------------
// Q only (K/V moved into attn). A-frag = one coalesced b128 from ABh-b.
// ---------------------------------------------------------------------------
__global__ __launch_bounds__(256) void q_mfma(const f16* __restrict__ ABh,
                                              const f16* __restrict__ bf,
                                              const float* __restrict__ qb,
                                              f16* __restrict__ Qh) {
  const int tid = threadIdx.x;
  const int lane = tid & 63, wave = tid >> 6;
  const int n = lane & 15, quad = lane >> 4;
  const f16* src = ABh + (size_t)NN * 32;  // stream b
  f16x8 QF[2];
#pragma unroll
  for (int nt = 0; nt < 2; ++nt)
    QF[nt] = *(const f16x8*)(bf + OQ + (nt * 64 + lane) * 8);
  float qbias[2];
#pragma unroll
  for (int nt = 0; nt < 2; ++nt) {
    int cc = nt * 16 + n;
    qbias[nt] = (cc < 24) ? qb[cc] : 0.f;
  }
#pragma unroll
  for (int t = 0; t < 4; ++t) {
    int T = blockIdx.x * 16 + wave * 4 + t;
    size_t p0 = (size_t)T * 16;
    f16x8 a8 = *(const f16x8*)(src + p0 * 32 + n * 32 + quad * 8);
#pragma unroll
    for (int nt = 0; nt < 2; ++nt) {
      f32x4 acc = {qbias[nt], qbias[nt], qbias[nt], qbias[nt]};
      acc = __builtin_amdgcn_mfma_f32_16x16x32_f16(a8, QF[nt], acc, 0, 0, 0);
      int cc = nt * 16 + n;
      if (cc < 24) {
#pragma unroll
        for (int reg = 0; reg < 4; ++reg)
          Qh[(p0 + quad * 4 + reg) * 24 + cc] = (f16)acc[reg];
      }
    }
  }
}

// ---------------------------------------------------------------------------
// Attention v3. 32x8 px tile, grid (8,32). Stage the a-HALO (64B/px, which IS
// MFMA A-layout) into 544 slots of 112B; snapshot own-center a; then each
// wave converts its 16-slot tiles IN PLACE to K[0:48B)|V[48:96B) via 4 MFMAs
// (wave-synchronous read-then-write, no barrier needed inside a tile). KVh
// global buffer eliminated entirely. Scores fdot2; PV packed-f16 FMA.
// ---------------------------------------------------------------------------
__device__ inline float dot8p(f16x8 a, f16x8 b, float acc) {
#if __has_builtin(__builtin_amdgcn_fdot2)
  acc = __builtin_amdgcn_fdot2(__builtin_shufflevector(a, a, 0, 1),
                               __builtin_shufflevector(b, b, 0, 1), acc, false);
  acc = __builtin_amdgcn_fdot2(__builtin_shufflevector(a, a, 2, 3),
                               __builtin_shufflevector(b, b, 2, 3), acc, false);
  acc = __builtin_amdgcn_fdot2(__builtin_shufflevector(a, a, 4, 5),
                               __builtin_shufflevector(b, b, 4, 5), acc, false);
  acc = __builtin_amdgcn_fdot2(__builtin_shufflevector(a, a, 6, 7),
                               __builtin_shufflevector(b, b, 6, 7), acc, false);
  return acc;
#else
#pragma unroll
  for (int i = 0; i < 8; ++i) acc += (float)a[i] * (float)b[i];
  return acc;
#endif
}

__global__ __launch_bounds__(256, 3) void attn_kernel(
    const f16* __restrict__ Qh, const f16* __restrict__ ABh,
    const f16* __restrict__ bf, const float* __restrict__ kb,
    const float* __restrict__ vb, float* __restrict__ out) {
  extern __shared__ f16 kv[];  // 544 slots * 56 f16 = 60928 B
  const int tid = threadIdx.x;
  const int lane = tid & 63, wave = tid >> 6;
  const int n16 = lane & 15, quad = lane >> 4;
  const int bx = blockIdx.x * 32, by = blockIdx.y * 8;
  const int xl = tid & 31, yl = tid >> 5;
  const int p = (by + yl) * WW + bx + xl;
  const f16* ah = ABh;                    // stream a
  const f16* bh = ABh + (size_t)NN * 32;  // stream b

  // Q loads issued early to overlap staging.
  f16x8 q0 = *(const f16x8*)(Qh + (size_t)p * 24);
  f16x8 q1 = *(const f16x8*)(Qh + (size_t)p * 24 + 8);
  f16x8 q2 = *(const f16x8*)(Qh + (size_t)p * 24 + 16);

  // ---- stage a-halo: 38x14 px, 64B/px -> slot f16[0:32)
  for (int idx = tid; idx < 2128; idx += 256) {
    int row = idx / 152;
    int rem = idx - row * 152;
    int pxl = rem >> 2;
    int c = rem & 3;
    int gy = by + row - 3, gx = bx + pxl - 3;
    f16x8 v = {};
    if (gy >= 0 && gy < HH && gx >= 0 && gx < WW)
      v = *(const f16x8*)(ah + ((size_t)(gy * WW + gx)) * 32 + c * 8);
    *(f16x8*)(kv + (row * 38 + pxl) * 56 + c * 8) = v;
  }
  __syncthreads();

  // ---- snapshot own-center a (ch 0..23) before in-place K/V overwrite
  const f16* cs = kv + ((yl + 3) * 38 + xl + 3) * 56;
  f16x8 a0 = *(const f16x8*)(cs);
  f16x8 a1 = *(const f16x8*)(cs + 8);
  f16x8 a2 = *(const f16x8*)(cs + 16);
  __syncthreads();

  // ---- in-place K/V: 34 tiles x 16 slots (slots 532..543 garbage, unread)
  {
    f16x8 KF[2], VF[2];
#pragma unroll
    for (int nt = 0; nt < 2; ++nt) {
      KF[nt] = *(const f16x8*)(bf + OQ + 1024 + (nt * 64 + lane) * 8);
      VF[nt] = *(const f16x8*)(bf + OQ + 2048 + (nt * 64 + lane) * 8);
    }
    float kbias[2], vbias[2];
#pragma unroll
    for (int nt = 0; nt < 2; ++nt) {
      int cc = nt * 16 + n16;
      kbias[nt] = (cc < 24) ? kb[cc] : 0.f;
      vbias[nt] = (cc < 24) ? vb[cc] : 0.f;
    }
    for (int t = wave; t < 34; t += 4) {
      f16x8 a8 = *(const f16x8*)(kv + (t * 16 + n16) * 56 + quad * 8);
#pragma unroll
      for (int nt = 0; nt < 2; ++nt) {
        f32x4 ak = {kbias[nt], kbias[nt], kbias[nt], kbias[nt]};
        f32x4 av = {vbias[nt], vbias[nt], vbias[nt], vbias[nt]};
        ak = __builtin_amdgcn_mfma_f32_16x16x32_f16(a8, KF[nt], ak, 0, 0, 0);
        av = __builtin_amdgcn_mfma_f32_16x16x32_f16(a8, VF[nt], av, 0, 0, 0);
        int cc = nt * 16 + n16;
        if (cc < 24) {
#pragma unroll
          for (int reg = 0; reg < 4; ++reg) {
            f16* slot = kv + (t * 16 + quad * 4 + reg) * 56;
            slot[cc] = (f16)ak[reg];       // K at f16 [0:24)
            slot[24 + cc] = (f16)av[reg];  // V at f16 [24:48)
          }
        }
      }
    }
  }
  __syncthreads();

  // ---- scores
  float s[49];
#pragma unroll
  for (int pp = 0; pp < 49; ++pp) {
    int dy = pp / 7, dx = pp - dy * 7;
    const f16* base = kv + ((yl + dy) * 38 + xl + dx) * 56;
    f16x8 k0 = *(const f16x8*)(base);
    f16x8 k1 = *(const f16x8*)(base + 8);
    f16x8 k2 = *(const f16x8*)(base + 16);
    float d = 0.f;
    d = dot8p(q0, k0, d);
    d = dot8p(q1, k1, d);
    d = dot8p(q2, k2, d);
    s[pp] = d * 0.20412414523193154f;  // 1/sqrt(24)
  }

  float m = s[0];
#pragma unroll
  for (int pp = 1; pp < 49; ++pp) m = fmaxf(m, s[pp]);
  float den = 0.f;
#pragma unroll
  for (int pp = 0; pp < 49; ++pp) {
    float e = __expf(s[pp] - m);
    s[pp] = e;
    den += e;
  }
  const float inv = 1.f / den;

  f16x8 y0 = {}, y1 = {}, y2 = {};
#pragma unroll
  for (int pp = 0; pp < 49; ++pp) {
    int dy = pp / 7, dx = pp - dy * 7;
    const f16* base = kv + ((yl + dy) * 38 + xl + dx) * 56 + 24;
    f16 wh = (f16)(s[pp] * inv);
    f16x8 w8 = {wh, wh, wh, wh, wh, wh, wh, wh};
    f16x8 v0 = *(const f16x8*)(base);
    f16x8 v1 = *(const f16x8*)(base + 8);
    f16x8 v2 = *(const f16x8*)(base + 16);
    y0 = v0 * w8 + y0;
    y1 = v1 * w8 + y1;
    y2 = v2 * w8 + y2;
  }

  f16x8 b0 = *(const f16x8*)(bh + (size_t)p * 32);
  f16x8 b1 = *(const f16x8*)(bh + (size_t)p * 32 + 8);
  f16x8 b2 = *(const f16x8*)(bh + (size_t)p * 32 + 16);
#pragma unroll
  for (int c = 0; c < 8; ++c) {
    out[(size_t)c * NN + p] = (float)y0[c] + (float)a0[c];
    out[(size_t)(8 + c) * NN + p] = (float)y1[c] + (float)a1[c];
    out[(size_t)(16 + c) * NN + p] = (float)y2[c] + (float)a2[c];
    out[(size_t)(24 + c) * NN + p] = (float)b0[c];
    out[(size_t)(32 + c) * NN + p] = (float)b1[c];
    out[(size_t)(40 + c) * NN + p] = (float)b2[c];
  }
}

// ---------------------------------------------------------------------------
extern "C" void kernel_launch(void* const* d_in, const int* in_sizes, int n_in,
                              void* d_out, int out_size, void* d_ws,
                              size_t ws_size, hipStream_t stream) {
  const float* x = (const float*)d_in[0];
  const float* w0 = (const float*)d_in[1];
  const float* b0 = (const float*)d_in[2];
  const float* w1 = (const float*)d_in[3];
  const float* b1 = (const float*)d_in[4];
  const float* w2 = (const float*)d_in[5];
  const float* b2 = (const float*)d_in[6];
  const float* w3 = (const float*)d_in[7];
  const float* b3 = (const float*)d_in[8];
  const float* sw = (const float*)d_in[9];
  const float* sb = (const float*)d_in[10];
  const float* qw = (const float*)d_in[11];
  const float* qb = (const float*)d_in[12];
  const float* kw = (const float*)d_in[13];
  const float* kb = (const float*)d_in[14];
  const float* vw = (const float*)d_in[15];
  const float* vb = (const float*)d_in[16];
  float* out = (float*)d_out;
  float* ws = (float*)d_ws;

  // workspace layout (float units), all regions disjoint:
  f16* Qh = (f16*)(ws);                       // NN*24 f16 = 12*NN floats
  f16* ABh = (f16*)(ws + (size_t)12 * NN);    // 2*NN*32 f16 = 32*NN floats
  f16* ACT0 = (f16*)(ws + (size_t)44 * NN);   // 2*NN*48 f16 = 48*NN floats
  f16* ACT1 = (f16*)(ws + (size_t)92 * NN);   // 48*NN floats
  f16* XH = (f16*)(ws + (size_t)140 * NN);    // 4*NN floats
  f16* BF = (f16*)(ws + (size_t)144 * NN);    // 78336 f16

  prep_kernel<<<dim3(818), dim3(256), 0, stream>>>(x, w0, w1, w2, w3, qw, kw,
                                                   vw, XH, BF);

  dim3 cgrd(16, 16, 2);
  conv0_gemm<<<cgrd, dim3(256), 256 * 80, stream>>>(XH, BF, b0, ACT0);
  gemm_conv<3, 48, false><<<cgrd, dim3(256), 324 * 144, stream>>>(
      ACT0, BF + 1536, b1, ACT1, nullptr, nullptr, nullptr);
  gemm_conv<3, 48, false><<<cgrd, dim3(256), 324 * 144, stream>>>(
      ACT1, BF + 29184, b2, ACT0, nullptr, nullptr, nullptr);
  gemm_conv<2, 24, true><<<cgrd, dim3(256), 324 * 144 + 3072, stream>>>(
      ACT0, BF + 56832, b3, ABh, x, sw, sb);

  q_mfma<<<dim3(256), dim3(256), 0, stream>>>(ABh, BF, qb, Qh);

  attn_kernel<<<dim3(8, 32), dim3(256), 544 * 112, stream>>>(Qh, ABh, BF, kb,
                                                             vb, out);
}